// Round 3
// baseline (429.178 us; speedup 1.0000x reference)
//
#include <hip/hip_runtime.h>

// CrossAttentionGAT — algebraically collapsed; edge path = coarse counting-bin
// (128 buckets of 64 nodes) + LDS-privatized per-bucket segment reduction.
// Fused into ONE plain (graph-capturable) kernel, 256x512, with a manual
// co-resident grid barrier (explicit agent-scope fences for cross-XCD
// visibility). Round-3 fix: P6 contraction is over k=0..1023 (was wrongly
// truncated to 128 in rounds 1-2 — deterministic wrong answer, same in both).
//
// mean(cross1) = mean(emb2) @ Wl + bl   (softmax col-sums == 1)
// mean(cross2) = mean(emb1) @ Wl + bl   (softmax row-sums == 1)
// mean(emb)    = (1/N) * sum_k g[head,k] * W[k, head*C+c] + b
//   g[head,k]  = sum_n w[n,head] x[n,k],  w[n,head] = sum_{e: src=n} alpha_e[head]

#define NN 8192
#define EE 262144
#define NEG 0.2f

#define BKT 128           // node buckets per graph
#define RNG (NN / BKT)    // 64 nodes per bucket
#define CAP 2560          // bucket capacity: mean 2048 + 11 sigma
#define EB  128           // bin blocks per graph
#define CHK (EE / EB)     // 2048 edges per bin block

// ---------------- ws layout (4-byte units) ----------------
#define U_CNT   0                        // 2 graphs x {D,S} x BKT ints (zeroed)
#define U_BAR   (U_CNT + 4*BKT + 64)     // pad; bar[0]=phase ctr, bar[1]=P5 done
#define U_G     (U_BAR + 16)             // 2*1024 floats (zeroed)
#define U_MEMB  (U_G + 2048)             // 2*1024 floats (zeroed)
#define U_ZEND  (U_MEMB + 2048)
#define U_U     (U_ZEND)                 // 2*2048 floats
#define U_ASRC  (U_U + 2*2048)           // 2*NN*8 floats
#define U_ADST  (U_ASRC + 2*NN*8)        // 2*NN*8 floats
#define U_PR    (U_ADST + 2*NN*8)        // 2*NN*16 floats: (adst,rden) float2
#define U_WACC  (U_PR + 2*NN*16)         // 2*NN*8 floats
#define U_BIND  (U_WACC + 2*NN*8)        // 2*BKT*CAP ints
#define U_BINS  (U_BIND + 2*BKT*CAP)     // 2*BKT*CAP ints
#define ZERO_BYTES ((size_t)U_ZEND * 4)

union SMem {
  struct { int hD[BKT]; int hS[BKT]; int bD[BKT]; int bS[BKT]; int cD[BKT]; int cS[BKT]; } bin;
  struct { float xs[64][129]; float us[16][128]; } a;     // 41.2 KB (max)
  struct { float den[RNG * 8]; float ad[RNG * 8]; } dr;
  struct { float wv[RNG * 8]; float as[RNG * 8]; } wr;
  float po[512];                                          // P6 partial sums
};

// Grid barrier for a fully co-resident grid (256 blocks x 512 thr; LDS allows
// 3 blocks/CU on 256 CUs -> any placement keeps all 256 resident).
__device__ __forceinline__ void gbar(int* bar, int target) {
  __threadfence();
  __syncthreads();
  if (threadIdx.x == 0) {
    __hip_atomic_fetch_add(bar, 1, __ATOMIC_RELAXED, __HIP_MEMORY_SCOPE_AGENT);
    while (__hip_atomic_load(bar, __ATOMIC_RELAXED, __HIP_MEMORY_SCOPE_AGENT) < target)
      __builtin_amdgcn_s_sleep(2);
    __threadfence();
  }
  __syncthreads();
}

__global__ __launch_bounds__(512, 1) void k_fused(
    const float* __restrict__ x1, const int* __restrict__ ei1,
    const float* __restrict__ W1, const float* __restrict__ as1,
    const float* __restrict__ ad1, const float* __restrict__ b1,
    const float* __restrict__ x2, const int* __restrict__ ei2,
    const float* __restrict__ W2, const float* __restrict__ as2,
    const float* __restrict__ ad2, const float* __restrict__ b2,
    const float* __restrict__ Wl, const float* __restrict__ bl,
    int* __restrict__ cnt, int* __restrict__ bar,
    float* __restrict__ gacc, float* __restrict__ memb,
    float* __restrict__ u, float* __restrict__ asrc, float* __restrict__ adst,
    float* __restrict__ pr, float* __restrict__ wacc,
    int* __restrict__ binD, int* __restrict__ binS, float* __restrict__ out) {
  __shared__ SMem sm;
  __shared__ int lastF;
  const int blk = (int)blockIdx.x;   // 0..255
  const int t = (int)threadIdx.x;    // 0..511

  // ---------------- P0: u[graph][sd][head][k] (blocks 224..255) ------------
  if (blk >= 224) {
    int b = blk - 224;                 // graph*16 + sd*8 + head
    int graph = b >> 4, sd = (b >> 3) & 1, head = b & 7;
    const float* W = graph ? W2 : W1;
    const float* att = graph ? (sd ? ad2 : as2) : (sd ? ad1 : as1);
    int w = t >> 6, lane = t & 63;     // 8 waves
    float2 av = ((const float2*)(att + head * 128))[lane];
    float* uo = u + graph * 2048 + sd * 1024 + head * 128;
    for (int k = w; k < 128; k += 8) {
      float2 wv = ((const float2*)(W + (size_t)k * 1024 + head * 128))[lane];
      float p = av.x * wv.x + av.y * wv.y;
      p += __shfl_xor(p, 1);  p += __shfl_xor(p, 2);  p += __shfl_xor(p, 4);
      p += __shfl_xor(p, 8);  p += __shfl_xor(p, 16); p += __shfl_xor(p, 32);
      if (lane == 0) uo[k] = p;
    }
  }
  gbar(bar, 256);

  // ---------------- P1: bin one 2048-edge chunk, then k_a 64-node tile ------
  {
    const int gph = blk >> 7;          // graph
    const int cb = blk & 127;          // chunk / node-tile index
    const int* ei = gph ? ei2 : ei1;
    for (int i = t; i < BKT; i += 512) {
      sm.bin.hD[i] = 0; sm.bin.hS[i] = 0; sm.bin.cD[i] = 0; sm.bin.cS[i] = 0;
    }
    __syncthreads();
    const int e0 = cb * CHK;
    for (int i = t; i < CHK; i += 512) {
      int s = ei[e0 + i], d = ei[EE + e0 + i];
      atomicAdd(&sm.bin.hD[d >> 6], 1);
      atomicAdd(&sm.bin.hS[s >> 6], 1);
    }
    __syncthreads();
    for (int i = t; i < BKT; i += 512) {
      sm.bin.bD[i] = atomicAdd(cnt + (2 * gph + 0) * BKT + i, sm.bin.hD[i]);
      sm.bin.bS[i] = atomicAdd(cnt + (2 * gph + 1) * BKT + i, sm.bin.hS[i]);
    }
    __syncthreads();
    int* bdg = binD + (size_t)gph * BKT * CAP;
    int* bsg = binS + (size_t)gph * BKT * CAP;
    for (int i = t; i < CHK; i += 512) {
      int s = ei[e0 + i], d = ei[EE + e0 + i];
      int kb = d >> 6;
      int p = sm.bin.bD[kb] + atomicAdd(&sm.bin.cD[kb], 1);
      bdg[kb * CAP + p] = (s << 6) | (d & 63);
      kb = s >> 6;
      p = sm.bin.bS[kb] + atomicAdd(&sm.bin.cS[kb], 1);
      bsg[kb * CAP + p] = (d << 6) | (s & 63);
    }
    __syncthreads();   // LDS union about to be reused

    // k_a: a_src/a_dst for this block's 64-node tile
    const float* x = gph ? x2 : x1;
    const float* ug = u + gph * 2048;
    for (int i = t; i < 2048; i += 512) sm.a.us[i >> 7][i & 127] = ug[i];
    const int n0 = cb * 64;
    const float* xb = x + (size_t)n0 * 128;
    for (int i = t; i < 64 * 128; i += 512) sm.a.xs[i >> 7][i & 127] = xb[i];
    __syncthreads();
    int nl = t & 63;
    int j0 = (t >> 6) * 2;             // 8 groups x 2 outputs = 16 (8 src + 8 dst)
    float a0 = 0.f, a1 = 0.f;
#pragma unroll 4
    for (int k = 0; k < 128; ++k) {
      float xv = sm.a.xs[nl][k];
      a0 += xv * sm.a.us[j0 + 0][k];
      a1 += xv * sm.a.us[j0 + 1][k];
    }
    int n = n0 + nl;
    float* outp = (j0 < 8) ? (asrc + gph * (NN * 8) + n * 8 + j0)
                           : (adst + gph * (NN * 8) + n * 8 + (j0 - 8));
    outp[0] = a0; outp[1] = a1;
  }
  gbar(bar, 512);

  // ---------------- P2: per dst-bucket denominator -> pr = (adst, 1/den) ----
  {
    const int gph = blk >> 7, b = blk & 127;
    const int lo = b * RNG;
    const float* as = asrc + gph * (NN * 8);
    const float* ad = adst + gph * (NN * 8);
    float2* prg = (float2*)pr + (size_t)gph * (NN * 8);
    for (int i = t; i < RNG * 8; i += 512) {
      float avv = ad[lo * 8 + i];
      float v = as[lo * 8 + i] + avv;      // self loop (s == d)
      v = v > 0.f ? v : NEG * v;
      sm.dr.ad[i] = avv;
      sm.dr.den[i] = __expf(v);
    }
    __syncthreads();
    int n = __hip_atomic_load(cnt + (2 * gph + 0) * BKT + b,
                              __ATOMIC_RELAXED, __HIP_MEMORY_SCOPE_AGENT);
    const int* recs = binD + (size_t)gph * BKT * CAP + b * CAP;
    int rid = t >> 3, h = t & 7;
    for (int base = 0; base < n; base += 256) {
      int rv[4]; bool ok[4]; float sv[4];
#pragma unroll
      for (int uu = 0; uu < 4; ++uu) {
        int i = base + uu * 64 + rid;
        ok[uu] = i < n;
        rv[uu] = ok[uu] ? recs[i] : 0;
      }
#pragma unroll
      for (int uu = 0; uu < 4; ++uu)
        sv[uu] = ok[uu] ? as[(rv[uu] >> 6) * 8 + h] : 0.f;
#pragma unroll
      for (int uu = 0; uu < 4; ++uu) {
        if (ok[uu]) {
          int dl = rv[uu] & 63;
          float v = sv[uu] + sm.dr.ad[dl * 8 + h];
          v = v > 0.f ? v : NEG * v;
          atomicAdd(&sm.dr.den[dl * 8 + h], __expf(v));
        }
      }
    }
    __syncthreads();
    for (int i = t; i < RNG * 8; i += 512)
      prg[lo * 8 + i] = make_float2(sm.dr.ad[i], 1.0f / sm.dr.den[i]);
  }
  gbar(bar, 768);

  // ---------------- P3: per src-bucket alpha-sum -> wacc --------------------
  {
    const int gph = blk >> 7, b = blk & 127;
    const int lo = b * RNG;
    const float* as = asrc + gph * (NN * 8);
    const float2* prg = (const float2*)pr + (size_t)gph * (NN * 8);
    for (int i = t; i < RNG * 8; i += 512) {
      float sva = as[lo * 8 + i];
      float2 f2 = prg[lo * 8 + i];         // (adst[n,h], rden[n,h])
      float v = sva + f2.x;                // self loop
      v = v > 0.f ? v : NEG * v;
      sm.wr.as[i] = sva;
      sm.wr.wv[i] = __expf(v) * f2.y;
    }
    __syncthreads();
    int n = __hip_atomic_load(cnt + (2 * gph + 1) * BKT + b,
                              __ATOMIC_RELAXED, __HIP_MEMORY_SCOPE_AGENT);
    const int* recs = binS + (size_t)gph * BKT * CAP + b * CAP;
    int rid = t >> 3, h = t & 7;
    for (int base = 0; base < n; base += 256) {
      int rv[4]; bool ok[4]; float2 pv[4];
#pragma unroll
      for (int uu = 0; uu < 4; ++uu) {
        int i = base + uu * 64 + rid;
        ok[uu] = i < n;
        rv[uu] = ok[uu] ? recs[i] : 0;
      }
#pragma unroll
      for (int uu = 0; uu < 4; ++uu)
        pv[uu] = ok[uu] ? prg[(size_t)(rv[uu] >> 6) * 8 + h] : make_float2(0.f, 0.f);
#pragma unroll
      for (int uu = 0; uu < 4; ++uu) {
        if (ok[uu]) {
          int sl = rv[uu] & 63;
          float v = sm.wr.as[sl * 8 + h] + pv[uu].x;
          v = v > 0.f ? v : NEG * v;
          atomicAdd(&sm.wr.wv[sl * 8 + h], __expf(v) * pv[uu].y);
        }
      }
    }
    __syncthreads();
    for (int i = t; i < RNG * 8; i += 512)
      wacc[gph * (NN * 8) + lo * 8 + i] = sm.wr.wv[i];
  }
  gbar(bar, 1024);

  // ---------------- P4: g[head,k] = sum_n w[n,head] x[n,k] (64-node chunks) -
  {
    const int gph = blk >> 7;
    const float* x = gph ? x2 : x1;
    const float* w = wacc + gph * (NN * 8);
    float* gg = gacc + gph * 1024;
    int k = t & 127;
    int h0 = (t >> 7) * 2;               // 4 groups x 2 heads
    int n0 = (blk & 127) * 64;
    float a0 = 0.f, a1 = 0.f;
#pragma unroll 4
    for (int n = n0; n < n0 + 64; ++n) {
      float xv = x[(size_t)n * 128 + k];
      float2 wv2 = *(const float2*)(w + (size_t)n * 8 + h0);
      a0 += xv * wv2.x; a1 += xv * wv2.y;
    }
    atomicAdd(gg + (h0 + 0) * 128 + k, a0);
    atomicAdd(gg + (h0 + 1) * 128 + k, a1);
  }
  gbar(bar, 1280);

  // ---------------- P5: memb += (1/N) g @ W (+bias), 32 blocks --------------
  if (blk >= 32) return;
  {
    int gph = blk >> 4, kc = (blk >> 1) & 7, eb = blk & 1;
    int e = eb * 512 + t;                // 0..1023
    const float* W = gph ? W2 : W1;
    const float* bb = gph ? b2 : b1;
    int head = e >> 7;
    const float* gr = gacc + gph * 1024 + head * 128;
    float s = 0.f;
#pragma unroll
    for (int k = kc * 16; k < kc * 16 + 16; ++k) s += gr[k] * W[(size_t)k * 1024 + e];
    s *= (1.0f / (float)NN);
    if (kc == 0) s += bb[e];
    atomicAdd(memb + gph * 1024 + e, s);
  }
  // last-arriving of the 32 P5 blocks computes the final projection
  __threadfence();
  __syncthreads();
  if (t == 0) {
    int prev = __hip_atomic_fetch_add(bar + 1, 1, __ATOMIC_ACQ_REL,
                                      __HIP_MEMORY_SCOPE_AGENT);
    lastF = (prev == 31);
  }
  __syncthreads();
  if (!lastF) return;
  __threadfence();   // acquire: see all 32 blocks' memb atomics

  // ---------------- P6: out = [memb(g2); memb(g1)] @ Wl + bl ----------------
  // Full contraction k=0..1023 (the rounds-1/2 bug was k<128). Split k into
  // two halves across the 512 threads, combine via LDS.
  {
    int o = t & 255;                     // output index
    int kh = t >> 8;                     // 0 or 1: k-half
    int j = o & 127;
    const float* m = (o < 128) ? (memb + 1024) : memb;
    float s = 0.f;
#pragma unroll 8
    for (int k = kh * 512; k < kh * 512 + 512; ++k)
      s += m[k] * Wl[(size_t)k * 128 + j];
    sm.po[t] = s;
    __syncthreads();
    if (t < 256) out[t] = sm.po[t] + sm.po[t + 256] + bl[t & 127];
  }
}

extern "C" void kernel_launch(void* const* d_in, const int* in_sizes, int n_in,
                              void* d_out, int out_size, void* d_ws, size_t ws_size,
                              hipStream_t stream) {
  const float* x1  = (const float*)d_in[0];
  const int*   ei1 = (const int*)d_in[1];
  const float* W1  = (const float*)d_in[2];
  const float* as1 = (const float*)d_in[3];
  const float* ad1 = (const float*)d_in[4];
  const float* b1  = (const float*)d_in[5];
  const float* x2  = (const float*)d_in[6];
  const int*   ei2 = (const int*)d_in[7];
  const float* W2  = (const float*)d_in[8];
  const float* as2 = (const float*)d_in[9];
  const float* ad2 = (const float*)d_in[10];
  const float* b2  = (const float*)d_in[11];
  const float* Wl  = (const float*)d_in[12];
  const float* bl  = (const float*)d_in[13];
  float* out = (float*)d_out;

  int*   cnt  = (int*)d_ws + U_CNT;
  int*   bar  = (int*)d_ws + U_BAR;
  float* gacc = (float*)d_ws + U_G;
  float* memb = (float*)d_ws + U_MEMB;
  float* u    = (float*)d_ws + U_U;
  float* asrc = (float*)d_ws + U_ASRC;
  float* adst = (float*)d_ws + U_ADST;
  float* pr   = (float*)d_ws + U_PR;
  float* wacc = (float*)d_ws + U_WACC;
  int*   binD = (int*)d_ws + U_BIND;
  int*   binS = (int*)d_ws + U_BINS;

  hipMemsetAsync(d_ws, 0, ZERO_BYTES, stream);  // cnt + bar + g + memb

  k_fused<<<256, 512, 0, stream>>>(
      x1, ei1, W1, as1, ad1, b1, x2, ei2, W2, as2, ad2, b2, Wl, bl,
      cnt, bar, gacc, memb, u, asrc, adst, pr, wacc, binD, binS, out);
}

// Round 4
// 288.988 us; speedup vs baseline: 1.4851x; 1.4851x over previous
//
#include <hip/hip_runtime.h>

// CrossAttentionGAT — algebraically collapsed; edge path = coarse counting-bin
// (128 buckets of 64 nodes) + LDS-privatized per-bucket segment reduction.
// ONE plain (graph-capturable) kernel, 256x512. Round-4: leader-only
// release/acquire grid barrier (was per-thread __threadfence = per-wave L2
// wb/inv storm -> 360us @ 2% VALU), and 5 barriers -> 2 + last-arrive:
//   u computed per-block in LDS; P3+P4 fused via LDS wv; P5+P6 in last block.
//
// mean(cross1) = mean(emb2) @ Wl + bl   (softmax col-sums == 1)
// mean(cross2) = mean(emb1) @ Wl + bl   (softmax row-sums == 1)
// mean(emb)    = (1/N) * sum_k g[head,k] * W[k, head*C+c] + b
//   g[head,k]  = sum_n w[n,head] x[n,k],  w[n,head] = sum_{e: src=n} alpha_e[head]

#define NN 8192
#define EE 262144
#define NEG 0.2f

#define BKT 128           // node buckets per graph
#define RNG (NN / BKT)    // 64 nodes per bucket
#define CAP 2560          // bucket capacity: mean 2048 + 11 sigma
#define CHK (EE / 128)    // 2048 edges per bin chunk

// ---------------- ws layout (4-byte units) ----------------
#define U_CNT   0                        // 2 graphs x {D,S} x BKT ints (zeroed)
#define U_BAR   (U_CNT + 4*BKT + 64)     // pad; bar[0]=phase ctr, bar[1]=last-arrive
#define U_GACC  (U_BAR + 16)             // 2*1024 floats (zeroed)
#define U_ZEND  (U_GACC + 2048)
#define U_ASRC  (U_ZEND)                 // 2*NN*8 floats
#define U_ADST  (U_ASRC + 2*NN*8)        // 2*NN*8 floats
#define U_PR    (U_ADST + 2*NN*8)        // 2*NN*16 floats: (adst,rden) float2
#define U_BIND  (U_PR + 2*NN*16)         // 2*BKT*CAP ints
#define U_BINS  (U_BIND + 2*BKT*CAP)     // 2*BKT*CAP ints
#define ZERO_BYTES ((size_t)U_ZEND * 4)

union SMem {
  struct { int hD[BKT]; int hS[BKT]; int bD[BKT]; int bS[BKT]; int cD[BKT]; int cS[BKT]; } bin;
  struct { float xs[64][129]; float us[16][128]; } a;     // 41.2 KB (max); us DISJOINT from bin
  struct { float den[RNG * 8]; float ad[RNG * 8]; } dr;
  struct { float wv[RNG * 8]; float as[RNG * 8]; } wr;
  struct { float memb[2][1024]; float po[512]; } f;       // last-block tail
};

// Grid barrier, fully co-resident grid (256 blocks x 512 thr, 1 block/CU).
// __syncthreads() drains vmcnt(0) (write-through L1 => block's stores are in
// L2); leader's RELEASE add emits ONE buffer_wbl2, ACQUIRE load ONE buffer_inv.
__device__ __forceinline__ void gbar(int* bar, int target) {
  __syncthreads();
  if (threadIdx.x == 0) {
    __hip_atomic_fetch_add(bar, 1, __ATOMIC_RELEASE, __HIP_MEMORY_SCOPE_AGENT);
    while (__hip_atomic_load(bar, __ATOMIC_RELAXED, __HIP_MEMORY_SCOPE_AGENT) < target)
      __builtin_amdgcn_s_sleep(2);
    (void)__hip_atomic_load(bar, __ATOMIC_ACQUIRE, __HIP_MEMORY_SCOPE_AGENT);
  }
  __syncthreads();
}

__global__ __launch_bounds__(512, 1) void k_fused(
    const float* __restrict__ x1, const int* __restrict__ ei1,
    const float* __restrict__ W1, const float* __restrict__ as1,
    const float* __restrict__ ad1, const float* __restrict__ b1,
    const float* __restrict__ x2, const int* __restrict__ ei2,
    const float* __restrict__ W2, const float* __restrict__ as2,
    const float* __restrict__ ad2, const float* __restrict__ b2,
    const float* __restrict__ Wl, const float* __restrict__ bl,
    int* __restrict__ cnt, int* __restrict__ bar, float* __restrict__ gacc,
    float* __restrict__ asrc, float* __restrict__ adst,
    float* __restrict__ pr,
    int* __restrict__ binD, int* __restrict__ binS, float* __restrict__ out) {
  __shared__ SMem sm;
  __shared__ int lastF;
  const int blk = (int)blockIdx.x;   // 0..255
  const int t = (int)threadIdx.x;    // 0..511
  const int gph = blk >> 7;          // graph
  const int cb = blk & 127;          // chunk / bucket / node-tile index

  // =========== Phase A: u (in-LDS) + bin chunk + k_a 64-node tile ==========
  // A1: u[sd][head][k] for this graph. Wave w = head w; lane covers 2 cols.
  // us rows 0..7 = src heads, 8..15 = dst heads (disjoint from sm.bin).
  {
    const float* Wg = gph ? W2 : W1;
    int w = t >> 6, lane = t & 63;
    float2 avs = ((const float2*)((gph ? as2 : as1) + w * 128))[lane];
    float2 avd = ((const float2*)((gph ? ad2 : ad1) + w * 128))[lane];
#pragma unroll 4
    for (int k = 0; k < 128; ++k) {
      float2 wv = ((const float2*)(Wg + (size_t)k * 1024 + w * 128))[lane];
      float ps = avs.x * wv.x + avs.y * wv.y;
      float pd = avd.x * wv.x + avd.y * wv.y;
      ps += __shfl_xor(ps, 1);  pd += __shfl_xor(pd, 1);
      ps += __shfl_xor(ps, 2);  pd += __shfl_xor(pd, 2);
      ps += __shfl_xor(ps, 4);  pd += __shfl_xor(pd, 4);
      ps += __shfl_xor(ps, 8);  pd += __shfl_xor(pd, 8);
      ps += __shfl_xor(ps, 16); pd += __shfl_xor(pd, 16);
      ps += __shfl_xor(ps, 32); pd += __shfl_xor(pd, 32);
      if (lane == 0) { sm.a.us[w][k] = ps; sm.a.us[8 + w][k] = pd; }
    }
  }
  // A2: bin one 2048-edge chunk (uses sm.bin, disjoint from us)
  {
    const int* ei = gph ? ei2 : ei1;
    for (int i = t; i < BKT; i += 512) {
      sm.bin.hD[i] = 0; sm.bin.hS[i] = 0; sm.bin.cD[i] = 0; sm.bin.cS[i] = 0;
    }
    __syncthreads();
    const int e0 = cb * CHK;
    for (int i = t; i < CHK; i += 512) {
      int s = ei[e0 + i], d = ei[EE + e0 + i];
      atomicAdd(&sm.bin.hD[d >> 6], 1);
      atomicAdd(&sm.bin.hS[s >> 6], 1);
    }
    __syncthreads();
    for (int i = t; i < BKT; i += 512) {
      sm.bin.bD[i] = atomicAdd(cnt + (2 * gph + 0) * BKT + i, sm.bin.hD[i]);
      sm.bin.bS[i] = atomicAdd(cnt + (2 * gph + 1) * BKT + i, sm.bin.hS[i]);
    }
    __syncthreads();
    int* bdg = binD + (size_t)gph * BKT * CAP;
    int* bsg = binS + (size_t)gph * BKT * CAP;
    for (int i = t; i < CHK; i += 512) {
      int s = ei[e0 + i], d = ei[EE + e0 + i];
      int kb = d >> 6;
      int p = sm.bin.bD[kb] + atomicAdd(&sm.bin.cD[kb], 1);
      bdg[kb * CAP + p] = (s << 6) | (d & 63);
      kb = s >> 6;
      p = sm.bin.bS[kb] + atomicAdd(&sm.bin.cS[kb], 1);
      bsg[kb * CAP + p] = (d << 6) | (s & 63);
    }
    __syncthreads();   // bin region about to be overwritten by xs
  }
  // A3: a_src/a_dst for this block's 64-node tile (reads sm.a.us)
  {
    const float* x = gph ? x2 : x1;
    const int n0 = cb * 64;
    const float* xb = x + (size_t)n0 * 128;
    for (int i = t; i < 64 * 128; i += 512) sm.a.xs[i >> 7][i & 127] = xb[i];
    __syncthreads();
    int nl = t & 63;
    int j0 = (t >> 6) * 2;             // 8 groups x 2 outputs = 16 (8 src + 8 dst)
    float a0 = 0.f, a1 = 0.f;
#pragma unroll 4
    for (int k = 0; k < 128; ++k) {
      float xv = sm.a.xs[nl][k];
      a0 += xv * sm.a.us[j0 + 0][k];
      a1 += xv * sm.a.us[j0 + 1][k];
    }
    int n = n0 + nl;
    float* outp = (j0 < 8) ? (asrc + gph * (NN * 8) + n * 8 + j0)
                           : (adst + gph * (NN * 8) + n * 8 + (j0 - 8));
    outp[0] = a0; outp[1] = a1;
  }
  gbar(bar, 256);

  // =========== Phase B: per dst-bucket denominator -> pr = (adst, 1/den) ====
  {
    const int lo = cb * RNG;
    const float* as = asrc + gph * (NN * 8);
    const float* ad = adst + gph * (NN * 8);
    float2* prg = (float2*)pr + (size_t)gph * (NN * 8);
    for (int i = t; i < RNG * 8; i += 512) {
      float avv = ad[lo * 8 + i];
      float v = as[lo * 8 + i] + avv;      // self loop (s == d)
      v = v > 0.f ? v : NEG * v;
      sm.dr.ad[i] = avv;
      sm.dr.den[i] = __expf(v);
    }
    __syncthreads();
    int n = __hip_atomic_load(cnt + (2 * gph + 0) * BKT + cb,
                              __ATOMIC_RELAXED, __HIP_MEMORY_SCOPE_AGENT);
    const int* recs = binD + (size_t)gph * BKT * CAP + cb * CAP;
    int rid = t >> 3, h = t & 7;
    for (int base = 0; base < n; base += 256) {
      int rv[4]; bool ok[4]; float sv[4];
#pragma unroll
      for (int uu = 0; uu < 4; ++uu) {
        int i = base + uu * 64 + rid;
        ok[uu] = i < n;
        rv[uu] = ok[uu] ? recs[i] : 0;
      }
#pragma unroll
      for (int uu = 0; uu < 4; ++uu)
        sv[uu] = ok[uu] ? as[(rv[uu] >> 6) * 8 + h] : 0.f;
#pragma unroll
      for (int uu = 0; uu < 4; ++uu) {
        if (ok[uu]) {
          int dl = rv[uu] & 63;
          float v = sv[uu] + sm.dr.ad[dl * 8 + h];
          v = v > 0.f ? v : NEG * v;
          atomicAdd(&sm.dr.den[dl * 8 + h], __expf(v));
        }
      }
    }
    __syncthreads();
    for (int i = t; i < RNG * 8; i += 512)
      prg[lo * 8 + i] = make_float2(sm.dr.ad[i], 1.0f / sm.dr.den[i]);
  }
  gbar(bar, 512);

  // =========== Phase C: src-bucket alpha-sum (LDS wv) + fused g-reduce ======
  {
    const int lo = cb * RNG;
    const float* as = asrc + gph * (NN * 8);
    const float2* prg = (const float2*)pr + (size_t)gph * (NN * 8);
    for (int i = t; i < RNG * 8; i += 512) {
      float sva = as[lo * 8 + i];
      float2 f2 = prg[lo * 8 + i];         // (adst[n,h], rden[n,h])
      float v = sva + f2.x;                // self loop
      v = v > 0.f ? v : NEG * v;
      sm.wr.as[i] = sva;
      sm.wr.wv[i] = __expf(v) * f2.y;
    }
    __syncthreads();
    int n = __hip_atomic_load(cnt + (2 * gph + 1) * BKT + cb,
                              __ATOMIC_RELAXED, __HIP_MEMORY_SCOPE_AGENT);
    const int* recs = binS + (size_t)gph * BKT * CAP + cb * CAP;
    int rid = t >> 3, h = t & 7;
    for (int base = 0; base < n; base += 256) {
      int rv[4]; bool ok[4]; float2 pv[4];
#pragma unroll
      for (int uu = 0; uu < 4; ++uu) {
        int i = base + uu * 64 + rid;
        ok[uu] = i < n;
        rv[uu] = ok[uu] ? recs[i] : 0;
      }
#pragma unroll
      for (int uu = 0; uu < 4; ++uu)
        pv[uu] = ok[uu] ? prg[(size_t)(rv[uu] >> 6) * 8 + h] : make_float2(0.f, 0.f);
#pragma unroll
      for (int uu = 0; uu < 4; ++uu) {
        if (ok[uu]) {
          int sl = rv[uu] & 63;
          float v = sm.wr.as[sl * 8 + h] + pv[uu].x;
          v = v > 0.f ? v : NEG * v;
          atomicAdd(&sm.wr.wv[sl * 8 + h], __expf(v) * pv[uu].y);
        }
      }
    }
    __syncthreads();
    // fused g-reduce: this bucket's 64 nodes, w from LDS (no wacc roundtrip)
    const float* x = gph ? x2 : x1;
    float* gg = gacc + gph * 1024;
    int k = t & 127;
    int h0 = (t >> 7) * 2;               // 4 groups x 2 heads
    int n0 = cb * RNG;
    float a0 = 0.f, a1 = 0.f;
#pragma unroll 4
    for (int nl = 0; nl < RNG; ++nl) {
      float xv = x[(size_t)(n0 + nl) * 128 + k];
      a0 += xv * sm.wr.wv[nl * 8 + h0];
      a1 += xv * sm.wr.wv[nl * 8 + h0 + 1];
    }
    atomicAdd(gg + (h0 + 0) * 128 + k, a0);
    atomicAdd(gg + (h0 + 1) * 128 + k, a1);
  }

  // =========== last-arriving block: memb (LDS) + final projection ===========
  __syncthreads();                       // drain this block's gacc atomics
  if (t == 0) {
    int prev = __hip_atomic_fetch_add(bar + 1, 1, __ATOMIC_ACQ_REL,
                                      __HIP_MEMORY_SCOPE_AGENT);
    lastF = (prev == 255);
  }
  __syncthreads();
  if (!lastF) return;

  // P5: memb[g][e] = (1/N) sum_{k<128} g[g,head(e),k] W[k,e] + b[e]  (in LDS)
  for (int o = t; o < 2048; o += 512) {
    int g2 = o >> 10, e = o & 1023;
    const float* W = g2 ? W2 : W1;
    const float* bb = g2 ? b2 : b1;
    const float* gr = gacc + g2 * 1024 + (e >> 7) * 128;
    float s = 0.f;
#pragma unroll 8
    for (int k = 0; k < 128; ++k) s += gr[k] * W[(size_t)k * 1024 + e];
    sm.f.memb[g2][e] = s * (1.0f / (float)NN) + bb[e];
  }
  __syncthreads();

  // P6: out = [memb(g2); memb(g1)] @ Wl + bl, k split in halves across threads
  {
    int o = t & 255;                     // output index
    int kh = t >> 8;                     // 0 or 1: k-half
    int j = o & 127;
    const float* m = (o < 128) ? sm.f.memb[1] : sm.f.memb[0];
    float s = 0.f;
#pragma unroll 8
    for (int k = kh * 512; k < kh * 512 + 512; ++k)
      s += m[k] * Wl[(size_t)k * 128 + j];
    sm.f.po[t] = s;
    __syncthreads();
    if (t < 256) out[t] = sm.f.po[t] + sm.f.po[t + 256] + bl[t & 127];
  }
}

extern "C" void kernel_launch(void* const* d_in, const int* in_sizes, int n_in,
                              void* d_out, int out_size, void* d_ws, size_t ws_size,
                              hipStream_t stream) {
  const float* x1  = (const float*)d_in[0];
  const int*   ei1 = (const int*)d_in[1];
  const float* W1  = (const float*)d_in[2];
  const float* as1 = (const float*)d_in[3];
  const float* ad1 = (const float*)d_in[4];
  const float* b1  = (const float*)d_in[5];
  const float* x2  = (const float*)d_in[6];
  const int*   ei2 = (const int*)d_in[7];
  const float* W2  = (const float*)d_in[8];
  const float* as2 = (const float*)d_in[9];
  const float* ad2 = (const float*)d_in[10];
  const float* b2  = (const float*)d_in[11];
  const float* Wl  = (const float*)d_in[12];
  const float* bl  = (const float*)d_in[13];
  float* out = (float*)d_out;

  int*   cnt  = (int*)d_ws + U_CNT;
  int*   bar  = (int*)d_ws + U_BAR;
  float* gacc = (float*)d_ws + U_GACC;
  float* asrc = (float*)d_ws + U_ASRC;
  float* adst = (float*)d_ws + U_ADST;
  float* pr   = (float*)d_ws + U_PR;
  int*   binD = (int*)d_ws + U_BIND;
  int*   binS = (int*)d_ws + U_BINS;

  hipMemsetAsync(d_ws, 0, ZERO_BYTES, stream);  // cnt + bar + gacc (~10 KB)

  k_fused<<<256, 512, 0, stream>>>(
      x1, ei1, W1, as1, ad1, b1, x2, ei2, W2, as2, ad2, b2, Wl, bl,
      cnt, bar, gacc, asrc, adst, pr, binD, binS, out);
}

// Round 5
// 281.776 us; speedup vs baseline: 1.5231x; 1.0256x over previous
//
#include <hip/hip_runtime.h>

// CrossAttentionGAT — algebraically collapsed; edge path = coarse counting-bin
// (128 buckets of 64 nodes) + LDS-privatized per-bucket segment reduction.
// ONE plain (graph-capturable) kernel, 256x512. Round-5: per-XCD cache
// maintenance. r4's leader-only barrier still had 256 leaders x (wbl2+inv)
// agent fences = 512 full L2 walks per sync (~60us each). Now: relaxed
// counting barrier in 3 stages; ONE maintainer block per XCD does the
// RELEASE (buffer_wbl2 sc1) and ACQUIRE (buffer_inv sc1) fences.
//
// mean(cross1) = mean(emb2) @ Wl + bl   (softmax col-sums == 1)
// mean(cross2) = mean(emb1) @ Wl + bl   (softmax row-sums == 1)
// mean(emb)    = (1/N) * sum_k g[head,k] * W[k, head*C+c] + b
//   g[head,k]  = sum_n w[n,head] x[n,k],  w[n,head] = sum_{e: src=n} alpha_e[head]

#define NN 8192
#define EE 262144
#define NEG 0.2f

#define BKT 128           // node buckets per graph
#define RNG (NN / BKT)    // 64 nodes per bucket
#define CAP 2560          // bucket capacity: mean 2048 + 11 sigma
#define CHK (EE / 128)    // 2048 edges per bin chunk

// ---------------- ws layout (4-byte units) ----------------
#define U_CNT   0                        // 2 graphs x {D,S} x BKT ints (zeroed)
#define U_CLM   (U_CNT + 4*BKT)          // [0..7] per-XCD claim counters
#define U_BAR   (U_CLM + 16)             // bar0@0 bar1@16 bar2@32 barF@48 (64B apart)
#define U_GACC  (U_BAR + 64)             // 2*1024 floats (zeroed)
#define U_ZEND  (U_GACC + 2048)
#define U_ASRC  (U_ZEND)                 // 2*NN*8 floats
#define U_ADST  (U_ASRC + 2*NN*8)        // 2*NN*8 floats
#define U_PR    (U_ADST + 2*NN*8)        // 2*NN*16 floats: (adst,rden) float2
#define U_BIND  (U_PR + 2*NN*16)         // 2*BKT*CAP ints
#define U_BINS  (U_BIND + 2*BKT*CAP)     // 2*BKT*CAP ints
#define ZERO_BYTES ((size_t)U_ZEND * 4)

union SMem {
  struct { int hD[BKT]; int hS[BKT]; int bD[BKT]; int bS[BKT]; int cD[BKT]; int cS[BKT]; } bin;
  struct { float xs[64][129]; float us[16][128]; } a;     // 41.2 KB (max); us DISJOINT from bin
  struct { float den[RNG * 8]; float ad[RNG * 8]; } dr;
  struct { float wv[RNG * 8]; float as[RNG * 8]; } wr;
  struct { float gld[2][1024]; float memb[2][1024]; float po[512]; } f;  // tail
};

#define A_LD(p)  __hip_atomic_load((p), __ATOMIC_RELAXED, __HIP_MEMORY_SCOPE_AGENT)
#define A_ADD(p, v) __hip_atomic_fetch_add((p), (v), __ATOMIC_RELAXED, __HIP_MEMORY_SCOPE_AGENT)

// 3-stage grid barrier, fully co-resident grid (256 blocks, 1/CU).
// Stage 1: all 256 blocks arrive (their stores are in their XCD L2 —
//          __syncthreads drained vmcnt). Stage 2: one maintainer per XCD
//          RELEASE-fences (ONE buffer_wbl2 sc1 walk per XCD) and arrives.
// Stage 3: maintainers ACQUIRE-fence (ONE buffer_inv sc1 per XCD), arrive.
// Targets for stages 2/3 use the counted number of claimed XCDs (robust to
// any block->XCD mapping). All counter atomics are relaxed (no hidden walks).
__device__ __forceinline__ void gsync(int* bar, const int* clm, int p, bool maint) {
  __syncthreads();
  if (threadIdx.x == 0) {
    A_ADD(bar + 0, 1);
    while (A_LD(bar + 0) < 256 * p) __builtin_amdgcn_s_sleep(2);
    int nxc = 0;                               // claims final once all arrived
#pragma unroll
    for (int i = 0; i < 8; ++i) nxc += (A_LD((int*)clm + i) != 0);
    if (maint) {
      __builtin_amdgcn_fence(__ATOMIC_RELEASE, "agent");   // wbl2 sc1 + waits
      A_ADD(bar + 16, 1);
    }
    while (A_LD(bar + 16) < nxc * p) __builtin_amdgcn_s_sleep(2);
    if (maint) {
      __builtin_amdgcn_fence(__ATOMIC_ACQUIRE, "agent");   // buffer_inv sc1
      A_ADD(bar + 32, 1);
    }
    while (A_LD(bar + 32) < nxc * p) __builtin_amdgcn_s_sleep(2);
  }
  __syncthreads();
}

__global__ __launch_bounds__(512, 1) void k_fused(
    const float* __restrict__ x1, const int* __restrict__ ei1,
    const float* __restrict__ W1, const float* __restrict__ as1,
    const float* __restrict__ ad1, const float* __restrict__ b1,
    const float* __restrict__ x2, const int* __restrict__ ei2,
    const float* __restrict__ W2, const float* __restrict__ as2,
    const float* __restrict__ ad2, const float* __restrict__ b2,
    const float* __restrict__ Wl, const float* __restrict__ bl,
    int* __restrict__ cnt, int* __restrict__ clm, int* __restrict__ bar,
    float* __restrict__ gacc,
    float* __restrict__ asrc, float* __restrict__ adst,
    float* __restrict__ pr,
    int* __restrict__ binD, int* __restrict__ binS, float* __restrict__ out) {
  __shared__ SMem sm;
  __shared__ int lastF;
  const int blk = (int)blockIdx.x;   // 0..255
  const int t = (int)threadIdx.x;    // 0..511
  const int gph = blk >> 7;          // graph
  const int cb = blk & 127;          // chunk / bucket / node-tile index

  // Claim per-XCD maintainer role (first block on each XCD wins).
  int xcc = 0;
  asm("s_getreg_b32 %0, hwreg(HW_REG_XCC_ID)" : "=s"(xcc));
  bool maint = false;
  if (t == 0) maint = (A_ADD(clm + (xcc & 7), 1) == 0);

  // =========== Phase A: u (in-LDS) + bin chunk + k_a 64-node tile ==========
  // A1: u[sd][head][k] for this graph. us rows 0..7 = src, 8..15 = dst
  // (us region is disjoint from sm.bin).
  {
    const float* Wg = gph ? W2 : W1;
    int w = t >> 6, lane = t & 63;
    float2 avs = ((const float2*)((gph ? as2 : as1) + w * 128))[lane];
    float2 avd = ((const float2*)((gph ? ad2 : ad1) + w * 128))[lane];
#pragma unroll 4
    for (int k = 0; k < 128; ++k) {
      float2 wv = ((const float2*)(Wg + (size_t)k * 1024 + w * 128))[lane];
      float ps = avs.x * wv.x + avs.y * wv.y;
      float pd = avd.x * wv.x + avd.y * wv.y;
      ps += __shfl_xor(ps, 1);  pd += __shfl_xor(pd, 1);
      ps += __shfl_xor(ps, 2);  pd += __shfl_xor(pd, 2);
      ps += __shfl_xor(ps, 4);  pd += __shfl_xor(pd, 4);
      ps += __shfl_xor(ps, 8);  pd += __shfl_xor(pd, 8);
      ps += __shfl_xor(ps, 16); pd += __shfl_xor(pd, 16);
      ps += __shfl_xor(ps, 32); pd += __shfl_xor(pd, 32);
      if (lane == 0) { sm.a.us[w][k] = ps; sm.a.us[8 + w][k] = pd; }
    }
  }
  // A2: bin one 2048-edge chunk (uses sm.bin, disjoint from us)
  {
    const int* ei = gph ? ei2 : ei1;
    for (int i = t; i < BKT; i += 512) {
      sm.bin.hD[i] = 0; sm.bin.hS[i] = 0; sm.bin.cD[i] = 0; sm.bin.cS[i] = 0;
    }
    __syncthreads();
    const int e0 = cb * CHK;
    for (int i = t; i < CHK; i += 512) {
      int s = ei[e0 + i], d = ei[EE + e0 + i];
      atomicAdd(&sm.bin.hD[d >> 6], 1);
      atomicAdd(&sm.bin.hS[s >> 6], 1);
    }
    __syncthreads();
    for (int i = t; i < BKT; i += 512) {
      sm.bin.bD[i] = atomicAdd(cnt + (2 * gph + 0) * BKT + i, sm.bin.hD[i]);
      sm.bin.bS[i] = atomicAdd(cnt + (2 * gph + 1) * BKT + i, sm.bin.hS[i]);
    }
    __syncthreads();
    int* bdg = binD + (size_t)gph * BKT * CAP;
    int* bsg = binS + (size_t)gph * BKT * CAP;
    for (int i = t; i < CHK; i += 512) {
      int s = ei[e0 + i], d = ei[EE + e0 + i];
      int kb = d >> 6;
      int p = sm.bin.bD[kb] + atomicAdd(&sm.bin.cD[kb], 1);
      bdg[kb * CAP + p] = (s << 6) | (d & 63);
      kb = s >> 6;
      p = sm.bin.bS[kb] + atomicAdd(&sm.bin.cS[kb], 1);
      bsg[kb * CAP + p] = (d << 6) | (s & 63);
    }
    __syncthreads();   // bin region about to be overwritten by xs
  }
  // A3: a_src/a_dst for this block's 64-node tile (reads sm.a.us)
  {
    const float* x = gph ? x2 : x1;
    const int n0 = cb * 64;
    const float* xb = x + (size_t)n0 * 128;
    for (int i = t; i < 64 * 128; i += 512) sm.a.xs[i >> 7][i & 127] = xb[i];
    __syncthreads();
    int nl = t & 63;
    int j0 = (t >> 6) * 2;             // 8 groups x 2 outputs = 16 (8 src + 8 dst)
    float a0 = 0.f, a1 = 0.f;
#pragma unroll 4
    for (int k = 0; k < 128; ++k) {
      float xv = sm.a.xs[nl][k];
      a0 += xv * sm.a.us[j0 + 0][k];
      a1 += xv * sm.a.us[j0 + 1][k];
    }
    int n = n0 + nl;
    float* outp = (j0 < 8) ? (asrc + gph * (NN * 8) + n * 8 + j0)
                           : (adst + gph * (NN * 8) + n * 8 + (j0 - 8));
    outp[0] = a0; outp[1] = a1;
  }
  gsync(bar, clm, 1, maint);

  // =========== Phase B: per dst-bucket denominator -> pr = (adst, 1/den) ====
  {
    const int lo = cb * RNG;
    const float* as = asrc + gph * (NN * 8);
    const float* ad = adst + gph * (NN * 8);
    float2* prg = (float2*)pr + (size_t)gph * (NN * 8);
    for (int i = t; i < RNG * 8; i += 512) {
      float avv = ad[lo * 8 + i];
      float v = as[lo * 8 + i] + avv;      // self loop (s == d)
      v = v > 0.f ? v : NEG * v;
      sm.dr.ad[i] = avv;
      sm.dr.den[i] = __expf(v);
    }
    __syncthreads();
    int n = A_LD(cnt + (2 * gph + 0) * BKT + cb);
    const int* recs = binD + (size_t)gph * BKT * CAP + cb * CAP;
    int rid = t >> 3, h = t & 7;
    for (int base = 0; base < n; base += 256) {
      int rv[4]; bool ok[4]; float sv[4];
#pragma unroll
      for (int uu = 0; uu < 4; ++uu) {
        int i = base + uu * 64 + rid;
        ok[uu] = i < n;
        rv[uu] = ok[uu] ? recs[i] : 0;
      }
#pragma unroll
      for (int uu = 0; uu < 4; ++uu)
        sv[uu] = ok[uu] ? as[(rv[uu] >> 6) * 8 + h] : 0.f;
#pragma unroll
      for (int uu = 0; uu < 4; ++uu) {
        if (ok[uu]) {
          int dl = rv[uu] & 63;
          float v = sv[uu] + sm.dr.ad[dl * 8 + h];
          v = v > 0.f ? v : NEG * v;
          atomicAdd(&sm.dr.den[dl * 8 + h], __expf(v));
        }
      }
    }
    __syncthreads();
    for (int i = t; i < RNG * 8; i += 512)
      prg[lo * 8 + i] = make_float2(sm.dr.ad[i], 1.0f / sm.dr.den[i]);
  }
  gsync(bar, clm, 2, maint);

  // =========== Phase C: src-bucket alpha-sum (LDS wv) + fused g-reduce ======
  {
    const int lo = cb * RNG;
    const float* as = asrc + gph * (NN * 8);
    const float2* prg = (const float2*)pr + (size_t)gph * (NN * 8);
    for (int i = t; i < RNG * 8; i += 512) {
      float sva = as[lo * 8 + i];
      float2 f2 = prg[lo * 8 + i];         // (adst[n,h], rden[n,h])
      float v = sva + f2.x;                // self loop
      v = v > 0.f ? v : NEG * v;
      sm.wr.as[i] = sva;
      sm.wr.wv[i] = __expf(v) * f2.y;
    }
    __syncthreads();
    int n = A_LD(cnt + (2 * gph + 1) * BKT + cb);
    const int* recs = binS + (size_t)gph * BKT * CAP + cb * CAP;
    int rid = t >> 3, h = t & 7;
    for (int base = 0; base < n; base += 256) {
      int rv[4]; bool ok[4]; float2 pv[4];
#pragma unroll
      for (int uu = 0; uu < 4; ++uu) {
        int i = base + uu * 64 + rid;
        ok[uu] = i < n;
        rv[uu] = ok[uu] ? recs[i] : 0;
      }
#pragma unroll
      for (int uu = 0; uu < 4; ++uu)
        pv[uu] = ok[uu] ? prg[(size_t)(rv[uu] >> 6) * 8 + h] : make_float2(0.f, 0.f);
#pragma unroll
      for (int uu = 0; uu < 4; ++uu) {
        if (ok[uu]) {
          int sl = rv[uu] & 63;
          float v = sm.wr.as[sl * 8 + h] + pv[uu].x;
          v = v > 0.f ? v : NEG * v;
          atomicAdd(&sm.wr.wv[sl * 8 + h], __expf(v) * pv[uu].y);
        }
      }
    }
    __syncthreads();
    // fused g-reduce: this bucket's 64 nodes, w from LDS (no wacc roundtrip)
    const float* x = gph ? x2 : x1;
    float* gg = gacc + gph * 1024;
    int k = t & 127;
    int h0 = (t >> 7) * 2;               // 4 groups x 2 heads
    int n0 = cb * RNG;
    float a0 = 0.f, a1 = 0.f;
#pragma unroll 4
    for (int nl = 0; nl < RNG; ++nl) {
      float xv = x[(size_t)(n0 + nl) * 128 + k];
      a0 += xv * sm.wr.wv[nl * 8 + h0];
      a1 += xv * sm.wr.wv[nl * 8 + h0 + 1];
    }
    atomicAdd(gg + (h0 + 0) * 128 + k, a0);     // device-scope RMW (coherent)
    atomicAdd(gg + (h0 + 1) * 128 + k, a1);
  }

  // =========== last-arriving block: memb (LDS) + final projection ===========
  __syncthreads();                       // drain this block's gacc atomics
  if (t == 0) {
    int prev = A_ADD(bar + 48, 1);       // relaxed: no cache walks here
    lastF = (prev == 255);
  }
  __syncthreads();
  if (!lastF) return;

  // Stage gacc into LDS via agent-scope atomic loads (values live at the
  // coherence point because they were produced by device-scope atomicAdds).
  for (int i = t; i < 2048; i += 512)
    sm.f.gld[i >> 10][i & 1023] = __hip_atomic_load(
        gacc + i, __ATOMIC_RELAXED, __HIP_MEMORY_SCOPE_AGENT);
  __syncthreads();

  // P5: memb[g][e] = (1/N) sum_{k<128} g[g,head(e),k] W[k,e] + b[e]  (in LDS)
  for (int o = t; o < 2048; o += 512) {
    int g2 = o >> 10, e = o & 1023;
    const float* W = g2 ? W2 : W1;
    const float* bb = g2 ? b2 : b1;
    const float* gr = &sm.f.gld[g2][(e >> 7) * 128];
    float s = 0.f;
#pragma unroll 8
    for (int k = 0; k < 128; ++k) s += gr[k] * W[(size_t)k * 1024 + e];
    sm.f.memb[g2][e] = s * (1.0f / (float)NN) + bb[e];
  }
  __syncthreads();

  // P6: out = [memb(g2); memb(g1)] @ Wl + bl, k split in halves across threads
  {
    int o = t & 255;                     // output index
    int kh = t >> 8;                     // 0 or 1: k-half
    int j = o & 127;
    const float* m = (o < 128) ? sm.f.memb[1] : sm.f.memb[0];
    float s = 0.f;
#pragma unroll 8
    for (int k = kh * 512; k < kh * 512 + 512; ++k)
      s += m[k] * Wl[(size_t)k * 128 + j];
    sm.f.po[t] = s;
    __syncthreads();
    if (t < 256) out[t] = sm.f.po[t] + sm.f.po[t + 256] + bl[t & 127];
  }
}

extern "C" void kernel_launch(void* const* d_in, const int* in_sizes, int n_in,
                              void* d_out, int out_size, void* d_ws, size_t ws_size,
                              hipStream_t stream) {
  const float* x1  = (const float*)d_in[0];
  const int*   ei1 = (const int*)d_in[1];
  const float* W1  = (const float*)d_in[2];
  const float* as1 = (const float*)d_in[3];
  const float* ad1 = (const float*)d_in[4];
  const float* b1  = (const float*)d_in[5];
  const float* x2  = (const float*)d_in[6];
  const int*   ei2 = (const int*)d_in[7];
  const float* W2  = (const float*)d_in[8];
  const float* as2 = (const float*)d_in[9];
  const float* ad2 = (const float*)d_in[10];
  const float* b2  = (const float*)d_in[11];
  const float* Wl  = (const float*)d_in[12];
  const float* bl  = (const float*)d_in[13];
  float* out = (float*)d_out;

  int*   cnt  = (int*)d_ws + U_CNT;
  int*   clm  = (int*)d_ws + U_CLM;
  int*   bar  = (int*)d_ws + U_BAR;
  float* gacc = (float*)d_ws + U_GACC;
  float* asrc = (float*)d_ws + U_ASRC;
  float* adst = (float*)d_ws + U_ADST;
  float* pr   = (float*)d_ws + U_PR;
  int*   binD = (int*)d_ws + U_BIND;
  int*   binS = (int*)d_ws + U_BINS;

  hipMemsetAsync(d_ws, 0, ZERO_BYTES, stream);  // cnt + clm + bar + gacc (~11 KB)

  k_fused<<<256, 512, 0, stream>>>(
      x1, ei1, W1, as1, ad1, b1, x2, ei2, W2, as2, ad2, b2, Wl, bl,
      cnt, clm, bar, gacc, asrc, adst, pr, binD, binS, out);
}

// Round 6
// 260.764 us; speedup vs baseline: 1.6459x; 1.0806x over previous
//
#include <hip/hip_runtime.h>

// CrossAttentionGAT — algebraically collapsed; edge path = coarse counting-bin
// (128 buckets of 64 nodes) + LDS-privatized per-bucket segment reduction.
// Round-6: BACK to multi-kernel (HW sync at kernel boundaries — empirically
// beats the manual grid barrier), keeping the r4/r5 algorithmic fusions:
//   k_aU  = u computed per-block in LDS + a_src/a_dst   (kills k_u)
//   k_waccG = src-bucket alpha-sum + fused g-reduce     (kills wacc array)
//   k_tail  = memb + final projection in ONE 1-block kernel (kills 2 kernels
//             + d_out memset)
// 6 dispatches total: memset(10KB) + k_bin + k_aU + k_den + k_waccG + k_tail.
//
// mean(cross1) = mean(emb2) @ Wl + bl   (softmax col-sums == 1)
// mean(cross2) = mean(emb1) @ Wl + bl   (softmax row-sums == 1)
// mean(emb)    = (1/N) * sum_k g[head,k] * W[k, head*C+c] + b
//   g[head,k]  = sum_n w[n,head] x[n,k],  w[n,head] = sum_{e: src=n} alpha_e[head]

#define NN 8192
#define EE 262144
#define NEG 0.2f

#define BKT 128           // node buckets per graph
#define RNG (NN / BKT)    // 64 nodes per bucket
#define CAP 2560          // bucket capacity: mean 2048 + 11 sigma
#define CHK (EE / 128)    // 2048 edges per bin chunk

// ---------------- ws layout (4-byte units) ----------------
#define U_CNT   0                        // 2 graphs x {D,S} x BKT ints (zeroed)
#define U_GACC  (U_CNT + 4*BKT)          // 2*1024 floats (zeroed)
#define U_ZEND  (U_GACC + 2048)
#define U_ASRC  (U_ZEND)                 // 2*NN*8 floats
#define U_ADST  (U_ASRC + 2*NN*8)        // 2*NN*8 floats
#define U_PR    (U_ADST + 2*NN*8)        // 2*NN*16 floats: (adst,rden) float2
#define U_BIND  (U_PR + 2*NN*16)         // 2*BKT*CAP ints
#define U_BINS  (U_BIND + 2*BKT*CAP)     // 2*BKT*CAP ints
#define ZERO_BYTES ((size_t)U_ZEND * 4)

// K1: bin edges by dst-bucket (payload s<<6|d%64) and src-bucket (d<<6|s%64).
__global__ __launch_bounds__(512) void k_bin(
    const int* __restrict__ ei1, const int* __restrict__ ei2,
    int* __restrict__ cnt, int* __restrict__ binD, int* __restrict__ binS) {
  int g = blockIdx.y;
  const int* ei = g ? ei2 : ei1;
  __shared__ int hD[BKT], hS[BKT], bD[BKT], bS[BKT], cD[BKT], cS[BKT];
  int t = threadIdx.x;
  for (int i = t; i < BKT; i += 512) { hD[i] = 0; hS[i] = 0; cD[i] = 0; cS[i] = 0; }
  __syncthreads();
  int e0 = blockIdx.x * CHK;
  for (int i = t; i < CHK; i += 512) {
    int s = ei[e0 + i], d = ei[EE + e0 + i];
    atomicAdd(&hD[d >> 6], 1);
    atomicAdd(&hS[s >> 6], 1);
  }
  __syncthreads();
  for (int i = t; i < BKT; i += 512) {
    bD[i] = atomicAdd(cnt + (2 * g + 0) * BKT + i, hD[i]);
    bS[i] = atomicAdd(cnt + (2 * g + 1) * BKT + i, hS[i]);
  }
  __syncthreads();
  int* bdg = binD + (size_t)g * BKT * CAP;
  int* bsg = binS + (size_t)g * BKT * CAP;
  for (int i = t; i < CHK; i += 512) {
    int s = ei[e0 + i], d = ei[EE + e0 + i];
    int kb = d >> 6;
    int p = bD[kb] + atomicAdd(&cD[kb], 1);
    bdg[kb * CAP + p] = (s << 6) | (d & 63);
    kb = s >> 6;
    p = bS[kb] + atomicAdd(&cS[kb], 1);
    bsg[kb * CAP + p] = (d << 6) | (s & 63);
  }
}

// K2: u in-LDS (per block, redundant but cheap) + a_src/a_dst 64-node tile.
__global__ __launch_bounds__(512, 1) void k_aU(
    const float* __restrict__ x1, const float* __restrict__ W1,
    const float* __restrict__ as1, const float* __restrict__ ad1,
    const float* __restrict__ x2, const float* __restrict__ W2,
    const float* __restrict__ as2, const float* __restrict__ ad2,
    float* __restrict__ asrc, float* __restrict__ adst) {
  int gph = blockIdx.y, cb = blockIdx.x;
  __shared__ float xs[64][129];
  __shared__ float us[16][128];       // rows 0..7 src heads, 8..15 dst heads
  int t = threadIdx.x;
  // u[sd][head][k] = att[head] . W[k, head*128:+128]
  {
    const float* Wg = gph ? W2 : W1;
    int w = t >> 6, lane = t & 63;
    float2 avs = ((const float2*)((gph ? as2 : as1) + w * 128))[lane];
    float2 avd = ((const float2*)((gph ? ad2 : ad1) + w * 128))[lane];
#pragma unroll 4
    for (int k = 0; k < 128; ++k) {
      float2 wv = ((const float2*)(Wg + (size_t)k * 1024 + w * 128))[lane];
      float ps = avs.x * wv.x + avs.y * wv.y;
      float pd = avd.x * wv.x + avd.y * wv.y;
      ps += __shfl_xor(ps, 1);  pd += __shfl_xor(pd, 1);
      ps += __shfl_xor(ps, 2);  pd += __shfl_xor(pd, 2);
      ps += __shfl_xor(ps, 4);  pd += __shfl_xor(pd, 4);
      ps += __shfl_xor(ps, 8);  pd += __shfl_xor(pd, 8);
      ps += __shfl_xor(ps, 16); pd += __shfl_xor(pd, 16);
      ps += __shfl_xor(ps, 32); pd += __shfl_xor(pd, 32);
      if (lane == 0) { us[w][k] = ps; us[8 + w][k] = pd; }
    }
  }
  const float* x = gph ? x2 : x1;
  const int n0 = cb * 64;
  const float* xb = x + (size_t)n0 * 128;
  for (int i = t; i < 64 * 128; i += 512) xs[i >> 7][i & 127] = xb[i];
  __syncthreads();
  int nl = t & 63;
  int j0 = (t >> 6) * 2;              // 8 groups x 2 outputs = 16 (8 src + 8 dst)
  float a0 = 0.f, a1 = 0.f;
#pragma unroll 4
  for (int k = 0; k < 128; ++k) {
    float xv = xs[nl][k];
    a0 += xv * us[j0 + 0][k];
    a1 += xv * us[j0 + 1][k];
  }
  int n = n0 + nl;
  float* outp = (j0 < 8) ? (asrc + gph * (NN * 8) + n * 8 + j0)
                         : (adst + gph * (NN * 8) + n * 8 + (j0 - 8));
  outp[0] = a0; outp[1] = a1;
}

// K3: per dst-bucket denominator -> pr = (adst, 1/den)
__global__ __launch_bounds__(512) void k_den(
    const int* __restrict__ cnt, const int* __restrict__ binD,
    const float* __restrict__ asrc, const float* __restrict__ adst,
    float* __restrict__ pr) {
  int gph = blockIdx.y, b = blockIdx.x;
  int lo = b * RNG;
  const float* as = asrc + gph * (NN * 8);
  const float* ad = adst + gph * (NN * 8);
  float2* prg = (float2*)pr + (size_t)gph * (NN * 8);
  __shared__ float den[RNG * 8];
  __shared__ float ads[RNG * 8];
  int t = threadIdx.x;
  for (int i = t; i < RNG * 8; i += 512) {
    float avv = ad[lo * 8 + i];
    float v = as[lo * 8 + i] + avv;      // self loop (s == d)
    v = v > 0.f ? v : NEG * v;
    ads[i] = avv;
    den[i] = __expf(v);
  }
  __syncthreads();
  int n = cnt[(2 * gph + 0) * BKT + b];
  const int* recs = binD + (size_t)gph * BKT * CAP + b * CAP;
  int rid = t >> 3, h = t & 7;
  for (int base = 0; base < n; base += 256) {
    int rv[4]; bool ok[4]; float sv[4];
#pragma unroll
    for (int uu = 0; uu < 4; ++uu) {
      int i = base + uu * 64 + rid;
      ok[uu] = i < n;
      rv[uu] = ok[uu] ? recs[i] : 0;
    }
#pragma unroll
    for (int uu = 0; uu < 4; ++uu)
      sv[uu] = ok[uu] ? as[(rv[uu] >> 6) * 8 + h] : 0.f;
#pragma unroll
    for (int uu = 0; uu < 4; ++uu) {
      if (ok[uu]) {
        int dl = rv[uu] & 63;
        float v = sv[uu] + ads[dl * 8 + h];
        v = v > 0.f ? v : NEG * v;
        atomicAdd(&den[dl * 8 + h], __expf(v));
      }
    }
  }
  __syncthreads();
  for (int i = t; i < RNG * 8; i += 512)
    prg[lo * 8 + i] = make_float2(ads[i], 1.0f / den[i]);
}

// K4: per src-bucket alpha-sum (LDS wv) + fused g-reduce (no wacc roundtrip).
__global__ __launch_bounds__(512) void k_waccG(
    const int* __restrict__ cnt, const int* __restrict__ binS,
    const float* __restrict__ asrc, const float* __restrict__ pr,
    const float* __restrict__ x1, const float* __restrict__ x2,
    float* __restrict__ gacc) {
  int gph = blockIdx.y, b = blockIdx.x;
  int lo = b * RNG;
  const float* as = asrc + gph * (NN * 8);
  const float2* prg = (const float2*)pr + (size_t)gph * (NN * 8);
  __shared__ float wv[RNG * 8];
  __shared__ float asx[RNG * 8];
  int t = threadIdx.x;
  for (int i = t; i < RNG * 8; i += 512) {
    float sva = as[lo * 8 + i];
    float2 f2 = prg[lo * 8 + i];         // (adst[n,h], rden[n,h])
    float v = sva + f2.x;                // self loop
    v = v > 0.f ? v : NEG * v;
    asx[i] = sva;
    wv[i] = __expf(v) * f2.y;
  }
  __syncthreads();
  int n = cnt[(2 * gph + 1) * BKT + b];
  const int* recs = binS + (size_t)gph * BKT * CAP + b * CAP;
  int rid = t >> 3, h = t & 7;
  for (int base = 0; base < n; base += 256) {
    int rv[4]; bool ok[4]; float2 pv[4];
#pragma unroll
    for (int uu = 0; uu < 4; ++uu) {
      int i = base + uu * 64 + rid;
      ok[uu] = i < n;
      rv[uu] = ok[uu] ? recs[i] : 0;
    }
#pragma unroll
    for (int uu = 0; uu < 4; ++uu)
      pv[uu] = ok[uu] ? prg[(size_t)(rv[uu] >> 6) * 8 + h] : make_float2(0.f, 0.f);
#pragma unroll
    for (int uu = 0; uu < 4; ++uu) {
      if (ok[uu]) {
        int sl = rv[uu] & 63;
        float v = asx[sl * 8 + h] + pv[uu].x;
        v = v > 0.f ? v : NEG * v;
        atomicAdd(&wv[sl * 8 + h], __expf(v) * pv[uu].y);
      }
    }
  }
  __syncthreads();
  // fused g-reduce: this bucket's 64 nodes, w straight from LDS
  const float* x = gph ? x2 : x1;
  float* gg = gacc + gph * 1024;
  int k = t & 127;
  int h0 = (t >> 7) * 2;               // 4 groups x 2 heads
  int n0 = b * RNG;
  float a0 = 0.f, a1 = 0.f;
#pragma unroll 4
  for (int nl = 0; nl < RNG; ++nl) {
    float xv = x[(size_t)(n0 + nl) * 128 + k];
    a0 += xv * wv[nl * 8 + h0];
    a1 += xv * wv[nl * 8 + h0 + 1];
  }
  atomicAdd(gg + (h0 + 0) * 128 + k, a0);
  atomicAdd(gg + (h0 + 1) * 128 + k, a1);
}

// K5 (1 block): memb[g][e] = (1/N) g@W + b (LDS), then out = memb @ Wl + bl.
__global__ __launch_bounds__(512) void k_tail(
    const float* __restrict__ gacc,
    const float* __restrict__ W1, const float* __restrict__ b1,
    const float* __restrict__ W2, const float* __restrict__ b2,
    const float* __restrict__ Wl, const float* __restrict__ bl,
    float* __restrict__ out) {
  __shared__ float gld[2][1024];
  __shared__ float memb[2][1024];
  __shared__ float po[512];
  int t = threadIdx.x;
  for (int i = t; i < 2048; i += 512) gld[i >> 10][i & 1023] = gacc[i];
  __syncthreads();
  for (int o = t; o < 2048; o += 512) {
    int g2 = o >> 10, e = o & 1023;
    const float* W = g2 ? W2 : W1;
    const float* bb = g2 ? b2 : b1;
    const float* gr = &gld[g2][(e >> 7) * 128];
    float s = 0.f;
#pragma unroll 8
    for (int k = 0; k < 128; ++k) s += gr[k] * W[(size_t)k * 1024 + e];
    memb[g2][e] = s * (1.0f / (float)NN) + bb[e];
  }
  __syncthreads();
  {
    int o = t & 255;                     // output index
    int kh = t >> 8;                     // 0 or 1: k-half
    int j = o & 127;
    const float* m = (o < 128) ? memb[1] : memb[0];
    float s = 0.f;
#pragma unroll 8
    for (int k = kh * 512; k < kh * 512 + 512; ++k)
      s += m[k] * Wl[(size_t)k * 128 + j];
    po[t] = s;
    __syncthreads();
    if (t < 256) out[t] = po[t] + po[t + 256] + bl[t & 127];
  }
}

extern "C" void kernel_launch(void* const* d_in, const int* in_sizes, int n_in,
                              void* d_out, int out_size, void* d_ws, size_t ws_size,
                              hipStream_t stream) {
  const float* x1  = (const float*)d_in[0];
  const int*   ei1 = (const int*)d_in[1];
  const float* W1  = (const float*)d_in[2];
  const float* as1 = (const float*)d_in[3];
  const float* ad1 = (const float*)d_in[4];
  const float* b1  = (const float*)d_in[5];
  const float* x2  = (const float*)d_in[6];
  const int*   ei2 = (const int*)d_in[7];
  const float* W2  = (const float*)d_in[8];
  const float* as2 = (const float*)d_in[9];
  const float* ad2 = (const float*)d_in[10];
  const float* b2  = (const float*)d_in[11];
  const float* Wl  = (const float*)d_in[12];
  const float* bl  = (const float*)d_in[13];
  float* out = (float*)d_out;

  int*   cnt  = (int*)d_ws + U_CNT;
  float* gacc = (float*)d_ws + U_GACC;
  float* asrc = (float*)d_ws + U_ASRC;
  float* adst = (float*)d_ws + U_ADST;
  float* pr   = (float*)d_ws + U_PR;
  int*   binD = (int*)d_ws + U_BIND;
  int*   binS = (int*)d_ws + U_BINS;

  hipMemsetAsync(d_ws, 0, ZERO_BYTES, stream);  // cnt + gacc (10 KB)

  k_bin<<<dim3(128, 2), 512, 0, stream>>>(ei1, ei2, cnt, binD, binS);
  k_aU<<<dim3(128, 2), 512, 0, stream>>>(x1, W1, as1, ad1, x2, W2, as2, ad2,
                                         asrc, adst);
  k_den<<<dim3(BKT, 2), 512, 0, stream>>>(cnt, binD, asrc, adst, pr);
  k_waccG<<<dim3(BKT, 2), 512, 0, stream>>>(cnt, binS, asrc, pr, x1, x2, gacc);
  k_tail<<<1, 512, 0, stream>>>(gacc, W1, b1, W2, b2, Wl, bl, out);
}

// Round 7
// 219.171 us; speedup vs baseline: 1.9582x; 1.1898x over previous
//
#include <hip/hip_runtime.h>

// CrossAttentionGAT — algebraically collapsed; edge path = coarse counting-bin
// (128 buckets of 64 nodes) + LDS-privatized per-bucket segment reduction.
// Round-7: u computed ONCE (2 rider blocks in k_bin's grid), not per-block in
// k_a — r6's k_aU redundantly recomputed u 256x (1536 shfl/thread) = 85us.
// 6 dispatches: memset(10KB) + k_bin(+u) + k_a + k_den + k_waccG + k_tail.
//
// mean(cross1) = mean(emb2) @ Wl + bl   (softmax col-sums == 1)
// mean(cross2) = mean(emb1) @ Wl + bl   (softmax row-sums == 1)
// mean(emb)    = (1/N) * sum_k g[head,k] * W[k, head*C+c] + b
//   g[head,k]  = sum_n w[n,head] x[n,k],  w[n,head] = sum_{e: src=n} alpha_e[head]

#define NN 8192
#define EE 262144
#define NEG 0.2f

#define BKT 128           // node buckets per graph
#define RNG (NN / BKT)    // 64 nodes per bucket
#define CAP 2560          // bucket capacity: mean 2048 + 11 sigma
#define CHK (EE / 128)    // 2048 edges per bin chunk

// ---------------- ws layout (4-byte units) ----------------
#define U_CNT   0                        // 2 graphs x {D,S} x BKT ints (zeroed)
#define U_GACC  (U_CNT + 4*BKT)          // 2*1024 floats (zeroed)
#define U_ZEND  (U_GACC + 2048)
#define U_U     (U_ZEND)                 // 2*2048 floats: u[g][sd*1024+head*128+k]
#define U_ASRC  (U_U + 2*2048)           // 2*NN*8 floats
#define U_ADST  (U_ASRC + 2*NN*8)        // 2*NN*8 floats
#define U_PR    (U_ADST + 2*NN*8)        // 2*NN*16 floats: (adst,rden) float2
#define U_BIND  (U_PR + 2*NN*16)         // 2*BKT*CAP ints
#define U_BINS  (U_BIND + 2*BKT*CAP)     // 2*BKT*CAP ints
#define ZERO_BYTES ((size_t)U_ZEND * 4)

// K1: bin edges by dst-bucket (payload s<<6|d%64) and src-bucket (d<<6|s%64).
// Rider blocks x=128 (sd=0/src) and x=129 (sd=1/dst) compute u for graph y:
//   u[head,k] = att[head,:] . W[k, head*128:+128]   (1024 outputs, 2/thread)
__global__ __launch_bounds__(512) void k_bin(
    const int* __restrict__ ei1, const int* __restrict__ ei2,
    const float* __restrict__ W1, const float* __restrict__ as1,
    const float* __restrict__ ad1,
    const float* __restrict__ W2, const float* __restrict__ as2,
    const float* __restrict__ ad2,
    int* __restrict__ cnt, int* __restrict__ binD, int* __restrict__ binS,
    float* __restrict__ u) {
  int g = blockIdx.y;
  int t = threadIdx.x;
  if (blockIdx.x >= 128) {               // u rider block
    int sd = blockIdx.x - 128;           // 0=src, 1=dst
    const float* Wg = g ? W2 : W1;
    const float* att = g ? (sd ? ad2 : as2) : (sd ? ad1 : as1);
    float* uo = u + g * 2048 + sd * 1024;
    for (int o = t; o < 1024; o += 512) {
      int head = o >> 7, k = o & 127;
      const float4* wr = (const float4*)(Wg + (size_t)k * 1024 + head * 128);
      const float4* ar = (const float4*)(att + head * 128);
      float s = 0.f;
#pragma unroll 8
      for (int c = 0; c < 32; ++c) {
        float4 w4 = wr[c], a4 = ar[c];
        s += w4.x * a4.x + w4.y * a4.y + w4.z * a4.z + w4.w * a4.w;
      }
      uo[o] = s;
    }
    return;
  }
  const int* ei = g ? ei2 : ei1;
  __shared__ int hD[BKT], hS[BKT], bD[BKT], bS[BKT], cD[BKT], cS[BKT];
  for (int i = t; i < BKT; i += 512) { hD[i] = 0; hS[i] = 0; cD[i] = 0; cS[i] = 0; }
  __syncthreads();
  int e0 = blockIdx.x * CHK;
  for (int i = t; i < CHK; i += 512) {
    int s = ei[e0 + i], d = ei[EE + e0 + i];
    atomicAdd(&hD[d >> 6], 1);
    atomicAdd(&hS[s >> 6], 1);
  }
  __syncthreads();
  for (int i = t; i < BKT; i += 512) {
    bD[i] = atomicAdd(cnt + (2 * g + 0) * BKT + i, hD[i]);
    bS[i] = atomicAdd(cnt + (2 * g + 1) * BKT + i, hS[i]);
  }
  __syncthreads();
  int* bdg = binD + (size_t)g * BKT * CAP;
  int* bsg = binS + (size_t)g * BKT * CAP;
  for (int i = t; i < CHK; i += 512) {
    int s = ei[e0 + i], d = ei[EE + e0 + i];
    int kb = d >> 6;
    int p = bD[kb] + atomicAdd(&cD[kb], 1);
    bdg[kb * CAP + p] = (s << 6) | (d & 63);
    kb = s >> 6;
    p = bS[kb] + atomicAdd(&cS[kb], 1);
    bsg[kb * CAP + p] = (d << 6) | (s & 63);
  }
}

// K2: a_src[n,h] = x[n,:] . u_src[h,:]; a_dst likewise. 64 nodes/block.
__global__ __launch_bounds__(512) void k_a(
    const float* __restrict__ x1, const float* __restrict__ x2,
    const float* __restrict__ u,
    float* __restrict__ asrc, float* __restrict__ adst) {
  int gph = blockIdx.y, cb = blockIdx.x;
  __shared__ float xs[64][129];
  __shared__ float us[16][128];       // rows 0..7 src heads, 8..15 dst heads
  int t = threadIdx.x;
  const float* ug = u + gph * 2048;
  for (int i = t; i < 2048; i += 512) us[i >> 7][i & 127] = ug[i];
  const float* x = gph ? x2 : x1;
  const int n0 = cb * 64;
  const float4* xb4 = (const float4*)(x + (size_t)n0 * 128);
  for (int i = t; i < 64 * 32; i += 512) {
    float4 v = xb4[i];
    int r = i >> 5, c = (i & 31) * 4;
    xs[r][c] = v.x; xs[r][c + 1] = v.y; xs[r][c + 2] = v.z; xs[r][c + 3] = v.w;
  }
  __syncthreads();
  int nl = t & 63;
  int j0 = (t >> 6) * 2;              // 8 groups x 2 outputs = 16 (8 src + 8 dst)
  float a0 = 0.f, a1 = 0.f;
#pragma unroll 4
  for (int k = 0; k < 128; ++k) {
    float xv = xs[nl][k];
    a0 += xv * us[j0 + 0][k];
    a1 += xv * us[j0 + 1][k];
  }
  int n = n0 + nl;
  float* outp = (j0 < 8) ? (asrc + gph * (NN * 8) + n * 8 + j0)
                         : (adst + gph * (NN * 8) + n * 8 + (j0 - 8));
  outp[0] = a0; outp[1] = a1;
}

// K3: per dst-bucket denominator -> pr = (adst, 1/den)
__global__ __launch_bounds__(512) void k_den(
    const int* __restrict__ cnt, const int* __restrict__ binD,
    const float* __restrict__ asrc, const float* __restrict__ adst,
    float* __restrict__ pr) {
  int gph = blockIdx.y, b = blockIdx.x;
  int lo = b * RNG;
  const float* as = asrc + gph * (NN * 8);
  const float* ad = adst + gph * (NN * 8);
  float2* prg = (float2*)pr + (size_t)gph * (NN * 8);
  __shared__ float den[RNG * 8];
  __shared__ float ads[RNG * 8];
  int t = threadIdx.x;
  for (int i = t; i < RNG * 8; i += 512) {
    float avv = ad[lo * 8 + i];
    float v = as[lo * 8 + i] + avv;      // self loop (s == d)
    v = v > 0.f ? v : NEG * v;
    ads[i] = avv;
    den[i] = __expf(v);
  }
  __syncthreads();
  int n = cnt[(2 * gph + 0) * BKT + b];
  const int* recs = binD + (size_t)gph * BKT * CAP + b * CAP;
  int rid = t >> 3, h = t & 7;
  for (int base = 0; base < n; base += 256) {
    int rv[4]; bool ok[4]; float sv[4];
#pragma unroll
    for (int uu = 0; uu < 4; ++uu) {
      int i = base + uu * 64 + rid;
      ok[uu] = i < n;
      rv[uu] = ok[uu] ? recs[i] : 0;
    }
#pragma unroll
    for (int uu = 0; uu < 4; ++uu)
      sv[uu] = ok[uu] ? as[(rv[uu] >> 6) * 8 + h] : 0.f;
#pragma unroll
    for (int uu = 0; uu < 4; ++uu) {
      if (ok[uu]) {
        int dl = rv[uu] & 63;
        float v = sv[uu] + ads[dl * 8 + h];
        v = v > 0.f ? v : NEG * v;
        atomicAdd(&den[dl * 8 + h], __expf(v));
      }
    }
  }
  __syncthreads();
  for (int i = t; i < RNG * 8; i += 512)
    prg[lo * 8 + i] = make_float2(ads[i], 1.0f / den[i]);
}

// K4: per src-bucket alpha-sum (LDS wv) + fused g-reduce (no wacc roundtrip).
__global__ __launch_bounds__(512) void k_waccG(
    const int* __restrict__ cnt, const int* __restrict__ binS,
    const float* __restrict__ asrc, const float* __restrict__ pr,
    const float* __restrict__ x1, const float* __restrict__ x2,
    float* __restrict__ gacc) {
  int gph = blockIdx.y, b = blockIdx.x;
  int lo = b * RNG;
  const float* as = asrc + gph * (NN * 8);
  const float2* prg = (const float2*)pr + (size_t)gph * (NN * 8);
  __shared__ float wv[RNG * 8];
  __shared__ float asx[RNG * 8];
  int t = threadIdx.x;
  for (int i = t; i < RNG * 8; i += 512) {
    float sva = as[lo * 8 + i];
    float2 f2 = prg[lo * 8 + i];         // (adst[n,h], rden[n,h])
    float v = sva + f2.x;                // self loop
    v = v > 0.f ? v : NEG * v;
    asx[i] = sva;
    wv[i] = __expf(v) * f2.y;
  }
  __syncthreads();
  int n = cnt[(2 * gph + 1) * BKT + b];
  const int* recs = binS + (size_t)gph * BKT * CAP + b * CAP;
  int rid = t >> 3, h = t & 7;
  for (int base = 0; base < n; base += 256) {
    int rv[4]; bool ok[4]; float2 pv[4];
#pragma unroll
    for (int uu = 0; uu < 4; ++uu) {
      int i = base + uu * 64 + rid;
      ok[uu] = i < n;
      rv[uu] = ok[uu] ? recs[i] : 0;
    }
#pragma unroll
    for (int uu = 0; uu < 4; ++uu)
      pv[uu] = ok[uu] ? prg[(size_t)(rv[uu] >> 6) * 8 + h] : make_float2(0.f, 0.f);
#pragma unroll
    for (int uu = 0; uu < 4; ++uu) {
      if (ok[uu]) {
        int sl = rv[uu] & 63;
        float v = asx[sl * 8 + h] + pv[uu].x;
        v = v > 0.f ? v : NEG * v;
        atomicAdd(&wv[sl * 8 + h], __expf(v) * pv[uu].y);
      }
    }
  }
  __syncthreads();
  // fused g-reduce: this bucket's 64 nodes, w straight from LDS
  const float* x = gph ? x2 : x1;
  float* gg = gacc + gph * 1024;
  int k = t & 127;
  int h0 = (t >> 7) * 2;               // 4 groups x 2 heads
  int n0 = b * RNG;
  float a0 = 0.f, a1 = 0.f;
#pragma unroll 4
  for (int nl = 0; nl < RNG; ++nl) {
    float xv = x[(size_t)(n0 + nl) * 128 + k];
    a0 += xv * wv[nl * 8 + h0];
    a1 += xv * wv[nl * 8 + h0 + 1];
  }
  atomicAdd(gg + (h0 + 0) * 128 + k, a0);
  atomicAdd(gg + (h0 + 1) * 128 + k, a1);
}

// K5 (1 block): memb[g][e] = (1/N) g@W + b (LDS), then out = memb @ Wl + bl.
__global__ __launch_bounds__(512) void k_tail(
    const float* __restrict__ gacc,
    const float* __restrict__ W1, const float* __restrict__ b1,
    const float* __restrict__ W2, const float* __restrict__ b2,
    const float* __restrict__ Wl, const float* __restrict__ bl,
    float* __restrict__ out) {
  __shared__ float gld[2][1024];
  __shared__ float memb[2][1024];
  __shared__ float po[512];
  int t = threadIdx.x;
  for (int i = t; i < 2048; i += 512) gld[i >> 10][i & 1023] = gacc[i];
  __syncthreads();
  for (int o = t; o < 2048; o += 512) {
    int g2 = o >> 10, e = o & 1023;
    const float* W = g2 ? W2 : W1;
    const float* bb = g2 ? b2 : b1;
    const float* gr = &gld[g2][(e >> 7) * 128];
    float s = 0.f;
#pragma unroll 8
    for (int k = 0; k < 128; ++k) s += gr[k] * W[(size_t)k * 1024 + e];
    memb[g2][e] = s * (1.0f / (float)NN) + bb[e];
  }
  __syncthreads();
  {
    int o = t & 255;                     // output index
    int kh = t >> 8;                     // 0 or 1: k-half
    int j = o & 127;
    const float* m = (o < 128) ? memb[1] : memb[0];
    float s = 0.f;
#pragma unroll 8
    for (int k = kh * 512; k < kh * 512 + 512; ++k)
      s += m[k] * Wl[(size_t)k * 128 + j];
    po[t] = s;
    __syncthreads();
    if (t < 256) out[t] = po[t] + po[t + 256] + bl[t & 127];
  }
}

extern "C" void kernel_launch(void* const* d_in, const int* in_sizes, int n_in,
                              void* d_out, int out_size, void* d_ws, size_t ws_size,
                              hipStream_t stream) {
  const float* x1  = (const float*)d_in[0];
  const int*   ei1 = (const int*)d_in[1];
  const float* W1  = (const float*)d_in[2];
  const float* as1 = (const float*)d_in[3];
  const float* ad1 = (const float*)d_in[4];
  const float* b1  = (const float*)d_in[5];
  const float* x2  = (const float*)d_in[6];
  const int*   ei2 = (const int*)d_in[7];
  const float* W2  = (const float*)d_in[8];
  const float* as2 = (const float*)d_in[9];
  const float* ad2 = (const float*)d_in[10];
  const float* b2  = (const float*)d_in[11];
  const float* Wl  = (const float*)d_in[12];
  const float* bl  = (const float*)d_in[13];
  float* out = (float*)d_out;

  int*   cnt  = (int*)d_ws + U_CNT;
  float* gacc = (float*)d_ws + U_GACC;
  float* u    = (float*)d_ws + U_U;
  float* asrc = (float*)d_ws + U_ASRC;
  float* adst = (float*)d_ws + U_ADST;
  float* pr   = (float*)d_ws + U_PR;
  int*   binD = (int*)d_ws + U_BIND;
  int*   binS = (int*)d_ws + U_BINS;

  hipMemsetAsync(d_ws, 0, ZERO_BYTES, stream);  // cnt + gacc (10 KB)

  k_bin<<<dim3(130, 2), 512, 0, stream>>>(ei1, ei2, W1, as1, ad1,
                                          W2, as2, ad2, cnt, binD, binS, u);
  k_a<<<dim3(128, 2), 512, 0, stream>>>(x1, x2, u, asrc, adst);
  k_den<<<dim3(BKT, 2), 512, 0, stream>>>(cnt, binD, asrc, adst, pr);
  k_waccG<<<dim3(BKT, 2), 512, 0, stream>>>(cnt, binS, asrc, pr, x1, x2, gacc);
  k_tail<<<1, 512, 0, stream>>>(gacc, W1, b1, W2, b2, Wl, bl, out);
}

// Round 8
// 179.260 us; speedup vs baseline: 2.3942x; 1.2226x over previous
//
#include <hip/hip_runtime.h>

// CrossAttentionGAT — algebraically collapsed; edge path = coarse counting-bin
// (128 buckets of 64 nodes) + LDS-privatized per-bucket segment reduction.
// Round-8: r7's 1-block k_tail (60us, latency-bound on 1 CU: 1.8MB stream at
// 13GB/s) split back into parallel k_memb (32 blocks, non-atomic) + k_out
// (32-block split-k atomicAdd, round-0-proven). 8 dispatches:
// memset(ws 10KB) + memset(out 1KB) + k_bin(+u riders) + k_a + k_den +
// k_waccG + k_memb + k_out.
//
// mean(cross1) = mean(emb2) @ Wl + bl   (softmax col-sums == 1)
// mean(cross2) = mean(emb1) @ Wl + bl   (softmax row-sums == 1)
// mean(emb)    = (1/N) * sum_k g[head,k] * W[k, head*C+c] + b
//   g[head,k]  = sum_n w[n,head] x[n,k],  w[n,head] = sum_{e: src=n} alpha_e[head]

#define NN 8192
#define EE 262144
#define NEG 0.2f

#define BKT 128           // node buckets per graph
#define RNG (NN / BKT)    // 64 nodes per bucket
#define CAP 2560          // bucket capacity: mean 2048 + 11 sigma
#define CHK (EE / 128)    // 2048 edges per bin chunk

// ---------------- ws layout (4-byte units) ----------------
#define U_CNT   0                        // 2 graphs x {D,S} x BKT ints (zeroed)
#define U_GACC  (U_CNT + 4*BKT)          // 2*1024 floats (zeroed)
#define U_ZEND  (U_GACC + 2048)
#define U_U     (U_ZEND)                 // 2*2048 floats: u[g][sd*1024+head*128+k]
#define U_MEMB  (U_U + 2*2048)           // 2*1024 floats (fully written by k_memb)
#define U_ASRC  (U_MEMB + 2048)          // 2*NN*8 floats
#define U_ADST  (U_ASRC + 2*NN*8)        // 2*NN*8 floats
#define U_PR    (U_ADST + 2*NN*8)        // 2*NN*16 floats: (adst,rden) float2
#define U_BIND  (U_PR + 2*NN*16)         // 2*BKT*CAP ints
#define U_BINS  (U_BIND + 2*BKT*CAP)     // 2*BKT*CAP ints
#define ZERO_BYTES ((size_t)U_ZEND * 4)

// K1: bin edges by dst-bucket (payload s<<6|d%64) and src-bucket (d<<6|s%64).
// Rider blocks x=128 (sd=0/src) and x=129 (sd=1/dst) compute u for graph y.
__global__ __launch_bounds__(512) void k_bin(
    const int* __restrict__ ei1, const int* __restrict__ ei2,
    const float* __restrict__ W1, const float* __restrict__ as1,
    const float* __restrict__ ad1,
    const float* __restrict__ W2, const float* __restrict__ as2,
    const float* __restrict__ ad2,
    int* __restrict__ cnt, int* __restrict__ binD, int* __restrict__ binS,
    float* __restrict__ u) {
  int g = blockIdx.y;
  int t = threadIdx.x;
  if (blockIdx.x >= 128) {               // u rider block
    int sd = blockIdx.x - 128;           // 0=src, 1=dst
    const float* Wg = g ? W2 : W1;
    const float* att = g ? (sd ? ad2 : as2) : (sd ? ad1 : as1);
    float* uo = u + g * 2048 + sd * 1024;
    for (int o = t; o < 1024; o += 512) {
      int head = o >> 7, k = o & 127;
      const float4* wr = (const float4*)(Wg + (size_t)k * 1024 + head * 128);
      const float4* ar = (const float4*)(att + head * 128);
      float s = 0.f;
#pragma unroll 8
      for (int c = 0; c < 32; ++c) {
        float4 w4 = wr[c], a4 = ar[c];
        s += w4.x * a4.x + w4.y * a4.y + w4.z * a4.z + w4.w * a4.w;
      }
      uo[o] = s;
    }
    return;
  }
  const int* ei = g ? ei2 : ei1;
  __shared__ int hD[BKT], hS[BKT], bD[BKT], bS[BKT], cD[BKT], cS[BKT];
  for (int i = t; i < BKT; i += 512) { hD[i] = 0; hS[i] = 0; cD[i] = 0; cS[i] = 0; }
  __syncthreads();
  int e0 = blockIdx.x * CHK;
  for (int i = t; i < CHK; i += 512) {
    int s = ei[e0 + i], d = ei[EE + e0 + i];
    atomicAdd(&hD[d >> 6], 1);
    atomicAdd(&hS[s >> 6], 1);
  }
  __syncthreads();
  for (int i = t; i < BKT; i += 512) {
    bD[i] = atomicAdd(cnt + (2 * g + 0) * BKT + i, hD[i]);
    bS[i] = atomicAdd(cnt + (2 * g + 1) * BKT + i, hS[i]);
  }
  __syncthreads();
  int* bdg = binD + (size_t)g * BKT * CAP;
  int* bsg = binS + (size_t)g * BKT * CAP;
  for (int i = t; i < CHK; i += 512) {
    int s = ei[e0 + i], d = ei[EE + e0 + i];
    int kb = d >> 6;
    int p = bD[kb] + atomicAdd(&cD[kb], 1);
    bdg[kb * CAP + p] = (s << 6) | (d & 63);
    kb = s >> 6;
    p = bS[kb] + atomicAdd(&cS[kb], 1);
    bsg[kb * CAP + p] = (d << 6) | (s & 63);
  }
}

// K2: a_src[n,h] = x[n,:] . u_src[h,:]; a_dst likewise. 64 nodes/block.
__global__ __launch_bounds__(512) void k_a(
    const float* __restrict__ x1, const float* __restrict__ x2,
    const float* __restrict__ u,
    float* __restrict__ asrc, float* __restrict__ adst) {
  int gph = blockIdx.y, cb = blockIdx.x;
  __shared__ float xs[64][129];
  __shared__ float us[16][128];       // rows 0..7 src heads, 8..15 dst heads
  int t = threadIdx.x;
  const float* ug = u + gph * 2048;
  for (int i = t; i < 2048; i += 512) us[i >> 7][i & 127] = ug[i];
  const float* x = gph ? x2 : x1;
  const int n0 = cb * 64;
  const float4* xb4 = (const float4*)(x + (size_t)n0 * 128);
  for (int i = t; i < 64 * 32; i += 512) {
    float4 v = xb4[i];
    int r = i >> 5, c = (i & 31) * 4;
    xs[r][c] = v.x; xs[r][c + 1] = v.y; xs[r][c + 2] = v.z; xs[r][c + 3] = v.w;
  }
  __syncthreads();
  int nl = t & 63;
  int j0 = (t >> 6) * 2;              // 8 groups x 2 outputs = 16 (8 src + 8 dst)
  float a0 = 0.f, a1 = 0.f;
#pragma unroll 4
  for (int k = 0; k < 128; ++k) {
    float xv = xs[nl][k];
    a0 += xv * us[j0 + 0][k];
    a1 += xv * us[j0 + 1][k];
  }
  int n = n0 + nl;
  float* outp = (j0 < 8) ? (asrc + gph * (NN * 8) + n * 8 + j0)
                         : (adst + gph * (NN * 8) + n * 8 + (j0 - 8));
  outp[0] = a0; outp[1] = a1;
}

// K3: per dst-bucket denominator -> pr = (adst, 1/den)
__global__ __launch_bounds__(512) void k_den(
    const int* __restrict__ cnt, const int* __restrict__ binD,
    const float* __restrict__ asrc, const float* __restrict__ adst,
    float* __restrict__ pr) {
  int gph = blockIdx.y, b = blockIdx.x;
  int lo = b * RNG;
  const float* as = asrc + gph * (NN * 8);
  const float* ad = adst + gph * (NN * 8);
  float2* prg = (float2*)pr + (size_t)gph * (NN * 8);
  __shared__ float den[RNG * 8];
  __shared__ float ads[RNG * 8];
  int t = threadIdx.x;
  for (int i = t; i < RNG * 8; i += 512) {
    float avv = ad[lo * 8 + i];
    float v = as[lo * 8 + i] + avv;      // self loop (s == d)
    v = v > 0.f ? v : NEG * v;
    ads[i] = avv;
    den[i] = __expf(v);
  }
  __syncthreads();
  int n = cnt[(2 * gph + 0) * BKT + b];
  const int* recs = binD + (size_t)gph * BKT * CAP + b * CAP;
  int rid = t >> 3, h = t & 7;
  for (int base = 0; base < n; base += 256) {
    int rv[4]; bool ok[4]; float sv[4];
#pragma unroll
    for (int uu = 0; uu < 4; ++uu) {
      int i = base + uu * 64 + rid;
      ok[uu] = i < n;
      rv[uu] = ok[uu] ? recs[i] : 0;
    }
#pragma unroll
    for (int uu = 0; uu < 4; ++uu)
      sv[uu] = ok[uu] ? as[(rv[uu] >> 6) * 8 + h] : 0.f;
#pragma unroll
    for (int uu = 0; uu < 4; ++uu) {
      if (ok[uu]) {
        int dl = rv[uu] & 63;
        float v = sv[uu] + ads[dl * 8 + h];
        v = v > 0.f ? v : NEG * v;
        atomicAdd(&den[dl * 8 + h], __expf(v));
      }
    }
  }
  __syncthreads();
  for (int i = t; i < RNG * 8; i += 512)
    prg[lo * 8 + i] = make_float2(ads[i], 1.0f / den[i]);
}

// K4: per src-bucket alpha-sum (LDS wv) + fused g-reduce (no wacc roundtrip).
__global__ __launch_bounds__(512) void k_waccG(
    const int* __restrict__ cnt, const int* __restrict__ binS,
    const float* __restrict__ asrc, const float* __restrict__ pr,
    const float* __restrict__ x1, const float* __restrict__ x2,
    float* __restrict__ gacc) {
  int gph = blockIdx.y, b = blockIdx.x;
  int lo = b * RNG;
  const float* as = asrc + gph * (NN * 8);
  const float2* prg = (const float2*)pr + (size_t)gph * (NN * 8);
  __shared__ float wv[RNG * 8];
  __shared__ float asx[RNG * 8];
  int t = threadIdx.x;
  for (int i = t; i < RNG * 8; i += 512) {
    float sva = as[lo * 8 + i];
    float2 f2 = prg[lo * 8 + i];         // (adst[n,h], rden[n,h])
    float v = sva + f2.x;                // self loop
    v = v > 0.f ? v : NEG * v;
    asx[i] = sva;
    wv[i] = __expf(v) * f2.y;
  }
  __syncthreads();
  int n = cnt[(2 * gph + 1) * BKT + b];
  const int* recs = binS + (size_t)gph * BKT * CAP + b * CAP;
  int rid = t >> 3, h = t & 7;
  for (int base = 0; base < n; base += 256) {
    int rv[4]; bool ok[4]; float2 pv[4];
#pragma unroll
    for (int uu = 0; uu < 4; ++uu) {
      int i = base + uu * 64 + rid;
      ok[uu] = i < n;
      rv[uu] = ok[uu] ? recs[i] : 0;
    }
#pragma unroll
    for (int uu = 0; uu < 4; ++uu)
      pv[uu] = ok[uu] ? prg[(size_t)(rv[uu] >> 6) * 8 + h] : make_float2(0.f, 0.f);
#pragma unroll
    for (int uu = 0; uu < 4; ++uu) {
      if (ok[uu]) {
        int sl = rv[uu] & 63;
        float v = asx[sl * 8 + h] + pv[uu].x;
        v = v > 0.f ? v : NEG * v;
        atomicAdd(&wv[sl * 8 + h], __expf(v) * pv[uu].y);
      }
    }
  }
  __syncthreads();
  // fused g-reduce: this bucket's 64 nodes, w straight from LDS
  const float* x = gph ? x2 : x1;
  float* gg = gacc + gph * 1024;
  int k = t & 127;
  int h0 = (t >> 7) * 2;               // 4 groups x 2 heads
  int n0 = b * RNG;
  float a0 = 0.f, a1 = 0.f;
#pragma unroll 4
  for (int nl = 0; nl < RNG; ++nl) {
    float xv = x[(size_t)(n0 + nl) * 128 + k];
    a0 += xv * wv[nl * 8 + h0];
    a1 += xv * wv[nl * 8 + h0 + 1];
  }
  atomicAdd(gg + (h0 + 0) * 128 + k, a0);
  atomicAdd(gg + (h0 + 1) * 128 + k, a1);
}

// K5: memb[g][e] = (1/N) sum_{k<128} gacc[g,head(e),k] W[k,e] + b[e].
// Grid (16,2): block owns 64 contiguous e (one head slice). Thread = (kc,el):
// kc=t>>6 covers 16 k; LDS-reduce 8 partials.
__global__ __launch_bounds__(512) void k_memb(
    const float* __restrict__ gacc,
    const float* __restrict__ W1, const float* __restrict__ b1,
    const float* __restrict__ W2, const float* __restrict__ b2,
    float* __restrict__ memb) {
  int g = blockIdx.y;
  int e0 = blockIdx.x * 64;
  const float* W = g ? W2 : W1;
  const float* bb = g ? b2 : b1;
  const float* gr = gacc + g * 1024 + (e0 >> 7) * 128;   // head const per block
  __shared__ float pm[8][64];
  int t = threadIdx.x;
  int el = t & 63, kc = t >> 6;        // kc = 0..7
  int e = e0 + el;
  float s = 0.f;
#pragma unroll
  for (int k = kc * 16; k < kc * 16 + 16; ++k)
    s += gr[k] * W[(size_t)k * 1024 + e];
  pm[kc][el] = s;
  __syncthreads();
  if (t < 64) {
    float acc = pm[0][el];
#pragma unroll
    for (int q = 1; q < 8; ++q) acc += pm[q][el];
    memb[g * 1024 + e] = acc * (1.0f / (float)NN) + bb[e];
  }
}

// K6: out = [memb(g2); memb(g1)] @ Wl + bl, split-k over 32 blocks (out zeroed).
__global__ __launch_bounds__(256) void k_out(
    const float* __restrict__ memb, const float* __restrict__ Wl,
    const float* __restrict__ bl, float* __restrict__ out) {
  int t = threadIdx.x;
  int j = t & 127;
  int k0 = blockIdx.x * 32;
  const float* m = (t < 128) ? (memb + 1024) : memb;
  float s = 0.f;
#pragma unroll
  for (int k = k0; k < k0 + 32; ++k) s += m[k] * Wl[(size_t)k * 128 + j];
  if (blockIdx.x == 0) s += bl[j];
  atomicAdd(out + t, s);
}

extern "C" void kernel_launch(void* const* d_in, const int* in_sizes, int n_in,
                              void* d_out, int out_size, void* d_ws, size_t ws_size,
                              hipStream_t stream) {
  const float* x1  = (const float*)d_in[0];
  const int*   ei1 = (const int*)d_in[1];
  const float* W1  = (const float*)d_in[2];
  const float* as1 = (const float*)d_in[3];
  const float* ad1 = (const float*)d_in[4];
  const float* b1  = (const float*)d_in[5];
  const float* x2  = (const float*)d_in[6];
  const int*   ei2 = (const int*)d_in[7];
  const float* W2  = (const float*)d_in[8];
  const float* as2 = (const float*)d_in[9];
  const float* ad2 = (const float*)d_in[10];
  const float* b2  = (const float*)d_in[11];
  const float* Wl  = (const float*)d_in[12];
  const float* bl  = (const float*)d_in[13];
  float* out = (float*)d_out;

  int*   cnt  = (int*)d_ws + U_CNT;
  float* gacc = (float*)d_ws + U_GACC;
  float* u    = (float*)d_ws + U_U;
  float* memb = (float*)d_ws + U_MEMB;
  float* asrc = (float*)d_ws + U_ASRC;
  float* adst = (float*)d_ws + U_ADST;
  float* pr   = (float*)d_ws + U_PR;
  int*   binD = (int*)d_ws + U_BIND;
  int*   binS = (int*)d_ws + U_BINS;

  hipMemsetAsync(d_ws, 0, ZERO_BYTES, stream);             // cnt + gacc (10 KB)
  hipMemsetAsync(d_out, 0, (size_t)out_size * 4, stream);  // split-k target

  k_bin<<<dim3(130, 2), 512, 0, stream>>>(ei1, ei2, W1, as1, ad1,
                                          W2, as2, ad2, cnt, binD, binS, u);
  k_a<<<dim3(128, 2), 512, 0, stream>>>(x1, x2, u, asrc, adst);
  k_den<<<dim3(BKT, 2), 512, 0, stream>>>(cnt, binD, asrc, adst, pr);
  k_waccG<<<dim3(BKT, 2), 512, 0, stream>>>(cnt, binS, asrc, pr, x1, x2, gacc);
  k_memb<<<dim3(16, 2), 512, 0, stream>>>(gacc, W1, b1, W2, b2, memb);
  k_out<<<32, 256, 0, stream>>>(memb, Wl, bl, out);
}